// Round 6
// baseline (466.904 us; speedup 1.0000x reference)
//
#include <hip/hip_runtime.h>
#include <hip/hip_fp16.h>

// Problem constants: B=1, L=2048, C=2048, H=16, D=128, keys = 2L = 4096
#define LQ 2048
#define CDIM 2048
#define NHEAD 16
#define HDIM 128
#define LKEY 4096

typedef _Float16 f16x8 __attribute__((ext_vector_type(8)));
typedef _Float16 f16x4 __attribute__((ext_vector_type(4)));
typedef float f32x4 __attribute__((ext_vector_type(4)));

#define GLOAD_LDS16(g, s) __builtin_amdgcn_global_load_lds( \
    (const __attribute__((address_space(1))) void*)(g),     \
    (__attribute__((address_space(3))) void*)(s), 16, 0, 0)

#define MFMA16(a, b, c) __builtin_amdgcn_mfma_f32_16x16x32_f16(a, b, c, 0, 0, 0)

__device__ __forceinline__ void storeC(float* p, float v) { *p = v; }
__device__ __forceinline__ void storeC(__half* p, float v) { *p = __float2half(v); }

// ---------------------------------------------------------------------------
// Shared GEMM body: C-tile = A[128bmA:+128, :K] * B[128bn:+128, :K]^T
// 128x128 tile, BK=64, 4 waves, 4x4 acc/wave, global_load_lds staging.
// MODE 0: plain store. MODE 1: fused rmsnorm+rope epilogue (fp16).
// MODE 2: transposed store into vTo[d][key].
// ---------------------------------------------------------------------------
template <int MODE, typename OutT>
__device__ __forceinline__ void gemm_body(
    __half* smem,
    const __half* __restrict__ A, const __half* __restrict__ B,
    OutT* __restrict__ C, int lda, int ldb, int ldc, int K,
    int bmA, int bmC, int bn,
    const float* __restrict__ wgt, int kmode, float oscale,
    __half* __restrict__ vTo)
{
    __half* lA = smem;
    __half* lB = smem + 8192;
    const int tid  = threadIdx.x;
    const int lane = tid & 63;
    const int wave = tid >> 6;
    const int r = tid >> 3;     // 0..31: row within 32-row staging slab
    const int g = tid & 7;      // 8-elem col group
    const __half* gA = A + (long)(bmA * 128 + r) * lda + ((g ^ (r & 7)) << 3);
    const __half* gB = B + (long)(bn * 128 + r) * ldb + ((g ^ (r & 7)) << 3);
    __half* lAp = lA + tid * 8;
    __half* lBp = lB + tid * 8;
    const int wr = (wave & 1) << 6;
    const int wc = (wave >> 1) << 6;
    const int l15 = lane & 15, quad = lane >> 4;

    f32x4 acc[4][4] = {};

    for (int kt = 0; kt < K; kt += 64) {
#pragma unroll
        for (int i = 0; i < 4; ++i) {
            GLOAD_LDS16(gA + (long)i * 32 * lda, lAp + i * 2048);
            GLOAD_LDS16(gB + (long)i * 32 * ldb, lBp + i * 2048);
        }
        gA += 64; gB += 64;
        __syncthreads();
#pragma unroll
        for (int kk = 0; kk < 2; ++kk) {
            f16x8 af[4], bfr[4];
#pragma unroll
            for (int mi = 0; mi < 4; ++mi) {
                const int m = wr + mi * 16 + l15;
                const int kg = kk * 4 + quad;
                af[mi] = *(const f16x8*)&lA[m * 64 + ((kg ^ (m & 7)) << 3)];
            }
#pragma unroll
            for (int ni = 0; ni < 4; ++ni) {
                const int n = wc + ni * 16 + l15;
                const int kg = kk * 4 + quad;
                bfr[ni] = *(const f16x8*)&lB[n * 64 + ((kg ^ (n & 7)) << 3)];
            }
#pragma unroll
            for (int mi = 0; mi < 4; ++mi)
#pragma unroll
                for (int ni = 0; ni < 4; ++ni)
                    acc[mi][ni] = MFMA16(af[mi], bfr[ni], acc[mi][ni]);
        }
        __syncthreads();
    }

    if constexpr (MODE == 0) {
        const int row0 = bmC * 128 + wr + quad * 4;
        const int col0 = bn * 128 + wc + l15;
#pragma unroll
        for (int mi = 0; mi < 4; ++mi)
#pragma unroll
            for (int ni = 0; ni < 4; ++ni)
#pragma unroll
                for (int rx = 0; rx < 4; ++rx)
                    storeC(&C[(long)(row0 + mi * 16 + rx) * ldc + col0 + ni * 16],
                           acc[mi][ni][rx]);
    } else if constexpr (MODE == 2) {
        // transposed store: vTo[d][key], d = tile col, key = tile row
#pragma unroll
        for (int mi = 0; mi < 4; ++mi)
#pragma unroll
            for (int ni = 0; ni < 4; ++ni)
#pragma unroll
                for (int rx = 0; rx < 4; ++rx) {
                    const int  d   = (bn - 16) * 128 + wc + ni * 16 + l15;
                    const long key = (long)bmC * 128 + wr + mi * 16 + quad * 4 + rx;
                    vTo[(long)d * LKEY + key] = __float2half(acc[mi][ni][rx]);
                }
    } else {
        // MODE 1: rmsnorm + rope fused. Tile cols = one head's D=128.
        __half* sT = smem;   // [128][136] fp16, aliases lA/lB (dead)
#pragma unroll
        for (int mi = 0; mi < 4; ++mi)
#pragma unroll
            for (int ni = 0; ni < 4; ++ni)
#pragma unroll
                for (int rx = 0; rx < 4; ++rx)
                    sT[(wr + mi * 16 + quad * 4 + rx) * 136 + wc + ni * 16 + l15] =
                        (_Float16)acc[mi][ni][rx];
        __syncthreads();
        const int row = (wave << 5) + (lane >> 1);   // 32 rows/wave
        const int c0  = (lane & 1) << 5;             // 0 or 32
        const __half* rp = sT + row * 136;
        f16x8 L[4], Hh[4];
#pragma unroll
        for (int j8 = 0; j8 < 4; ++j8) {
            L[j8]  = *(const f16x8*)&rp[c0 + j8 * 8];
            Hh[j8] = *(const f16x8*)&rp[c0 + 64 + j8 * 8];
        }
        float ss = 0.f;
#pragma unroll
        for (int j8 = 0; j8 < 4; ++j8)
#pragma unroll
            for (int e = 0; e < 8; ++e) {
                const float a = (float)L[j8][e], b = (float)Hh[j8][e];
                ss += a * a + b * b;
            }
        ss += __shfl_xor(ss, 1);                     // lane-pair -> full 128
        const float rn = rsqrtf(ss * (1.0f / 128.0f) + 1e-6f);
        const long grow = (long)bmC * 128 + row;
        const int depth = kmode ? (grow < 2048 ? 0 : 1) : 2;
        union { f16x8 v; _Float16 e[8]; } o1[4], o2[4];
#pragma unroll
        for (int j8 = 0; j8 < 4; ++j8)
#pragma unroll
            for (int e = 0; e < 8; ++e) {
                const int d = c0 + j8 * 8 + e;
                const float x1 = (float)L[j8][e]  * rn * wgt[d];
                const float x2 = (float)Hh[j8][e] * rn * wgt[d + 64];
                const float ang = (float)depth *
                    exp2f(-(float)d * 0.20762050593045702f);
                float sn, cs;
                __sincosf(ang, &sn, &cs);
                o1[j8].e[e] = (_Float16)((x1 * cs - x2 * sn) * oscale);
                o2[j8].e[e] = (_Float16)((x1 * sn + x2 * cs) * oscale);
            }
        __half* op = (__half*)C + grow * ldc + bn * 128;
#pragma unroll
        for (int j8 = 0; j8 < 4; ++j8) {
            *(f16x8*)&op[c0 + j8 * 8]      = o1[j8].v;
            *(f16x8*)&op[c0 + 64 + j8 * 8] = o2[j8].v;
        }
    }
}

// ---------------------------------------------------------------------------
// Fused Q+KV projection GEMM (1280 blocks). LDS 34.8KB + VGPR 64 fit
// 4 blocks/CU -> 1280/1024 slots = 1.25 dispatch rounds (was (256,2):
// 2.5 rounds, 30% occupancy -> the measured 101us / 848TF ceiling).
// ---------------------------------------------------------------------------
__global__ __launch_bounds__(256, 4) void gemm_qkv(
    const __half* __restrict__ A, const __half* __restrict__ Bq,
    const __half* __restrict__ Bkv, __half* __restrict__ Cq,
    __half* __restrict__ Ckv, __half* __restrict__ vT,
    const float* __restrict__ qn_w, const float* __restrict__ kn_w)
{
    __shared__ __align__(16) __half smem[17408];
    const int lin = blockIdx.x;
    if (lin < 1024) {
        const int bm = lin & 31, bn = lin >> 5;
        if (bn < 16)
            gemm_body<1, __half>(smem, A, Bkv, Ckv, 2048, 2048, 4096, 2048,
                                 bm + 16, bm, bn, kn_w, 1, 1.0f, nullptr);
        else
            gemm_body<2, __half>(smem, A, Bkv, Ckv, 2048, 2048, 4096, 2048,
                                 bm + 16, bm, bn, nullptr, 0, 1.0f, vT);
    } else {
        const int l2 = lin - 1024;
        const int bm = l2 & 15, bn = l2 >> 4;
        gemm_body<1, __half>(smem, A, Bq, Cq, 2048, 2048, 2048, 2048,
                             bm, bm, bn, qn_w, 0, 0.12751743f, nullptr);
    }
}

// ---------------------------------------------------------------------------
// Split-K x2 final GEMM: grid (16,16,2) = 512 blocks at up to 4/CU.
// (x4 doubled partial-write traffic for no fill benefit.)
// ---------------------------------------------------------------------------
__global__ __launch_bounds__(256, 4) void gemm_sk(
    const __half* __restrict__ A, const __half* __restrict__ B,
    float* __restrict__ C, int lda, int ldb, int ldc, int Khalf)
{
    __shared__ __align__(16) __half smem[16384];
    const int z = blockIdx.z;
    gemm_body<0, float>(smem, A + z * Khalf, B + z * Khalf,
                        C + (long)z * LQ * CDIM,
                        lda, ldb, ldc, Khalf, blockIdx.x, blockIdx.x, blockIdx.y,
                        nullptr, 0, 1.0f, nullptr);
}

// ---------------------------------------------------------------------------
// Fused attention tile kernel (max-free softmax, log2-domain scores).
// Best-measured structure (v1/v5), unchanged. Grid (16, 32 = head*2+kc).
// ---------------------------------------------------------------------------
__global__ __launch_bounds__(256, 2) void attn_tile(
    const __half* __restrict__ Qf,  // [2048][2048] normed+roped, log2-scaled
    const __half* __restrict__ Kf,  // kvf [4096][4096]; K in cols 0..2047
    const __half* __restrict__ Vt,  // [2048][4096]  Vt[h*128+d][key]
    float* __restrict__ Opart,      // [2][2048][2048]
    float* __restrict__ lsum)       // [16][2048]
{
    __shared__ __align__(16) __half lK[64 * 128];   // 16 KB
    __shared__ __align__(16) __half lV[128 * 64];   // 16 KB
    __shared__ __align__(16) __half pL[4 * 2 * 16 * 76];  // 19 KB

    const int tid  = threadIdx.x;
    const int lane = tid & 63;
    const int wave = tid >> 6;
    const int l15  = lane & 15;
    const int quad = lane >> 4;
    const int h  = blockIdx.y >> 1;
    const int kc = blockIdx.y & 1;
    const int q0 = blockIdx.x * 128 + wave * 32;   // this wave's 32 q-rows

    // Q A-fragments: A[m=l15][k=ks*32+quad*8+j]
    f16x8 aq[2][4];
#pragma unroll
    for (int mt = 0; mt < 2; ++mt)
#pragma unroll
        for (int ks = 0; ks < 4; ++ks)
            aq[mt][ks] = *(const f16x8*)&Qf[(long)(q0 + mt * 16 + l15) * CDIM +
                                            h * HDIM + ks * 32 + quad * 8];

    // staging pointers. LDS[r][g] = global[r][g ^ (r & mask)] (XOR swizzle in
    // the SOURCE address; LDS dest is wave-uniform base + lane*16).
    const int rK = tid >> 4;          // K row 0..15 (+16/issue)
    const int gK = tid & 15;          // 16 groups of 8 halves
    const __half* srcK = Kf + (long)(kc * 2048 + rK) * 4096 + h * HDIM +
                         ((gK ^ (rK & 15)) << 3);
    const int rV = tid >> 3;          // V row (d) 0..31 (+32/issue)
    const int gV = tid & 7;           // 8 groups of 8 halves
    const __half* srcV = Vt + (long)(h * HDIM + rV) * (long)LKEY + kc * 2048 +
                         ((gV ^ (rV & 7)) << 3);
    __half* dstK = lK + tid * 8;
    __half* dstV = lV + tid * 8;

    f32x4 accO[2][8] = {};
    f32x4 l_acc[2] = {};

    for (int st = 0; st < 32; ++st) {
#pragma unroll
        for (int i = 0; i < 4; ++i) {
            GLOAD_LDS16(srcK + (long)(st * 64 + i * 16) * 4096, dstK + i * 2048);
            GLOAD_LDS16(srcV + (long)i * 32 * LKEY + st * 64, dstV + i * 2048);
        }
        __syncthreads();
        // ---- QK^T (acc init -10 folds the exp2 bias) ----
        f32x4 s[2][4];
#pragma unroll
        for (int mt = 0; mt < 2; ++mt)
#pragma unroll
            for (int nt = 0; nt < 4; ++nt)
                s[mt][nt] = (f32x4){-10.f, -10.f, -10.f, -10.f};
#pragma unroll
        for (int nt = 0; nt < 4; ++nt) {
            const int n = nt * 16 + l15;
#pragma unroll
            for (int ks = 0; ks < 4; ++ks) {
                const f16x8 kf = *(const f16x8*)
                    &lK[n * 128 + (((ks * 4 + quad) ^ (n & 15)) << 3)];
                s[0][nt] = MFMA16(aq[0][ks], kf, s[0][nt]);
                s[1][nt] = MFMA16(aq[1][ks], kf, s[1][nt]);
            }
        }
        // ---- P = exp2(s), accumulate l, stage P (per-wave slab) ----
#pragma unroll
        for (int mt = 0; mt < 2; ++mt)
#pragma unroll
            for (int nt = 0; nt < 4; ++nt)
#pragma unroll
                for (int r2 = 0; r2 < 4; ++r2) {
                    const float p = __builtin_amdgcn_exp2f(s[mt][nt][r2]);
                    l_acc[mt][r2] += p;
                    pL[((wave * 2 + mt) * 16 + quad * 4 + r2) * 76 +
                       nt * 16 + l15] = __float2half(p);
                }
        // ---- PV ----
        f16x8 ap[2][2];
#pragma unroll
        for (int mt = 0; mt < 2; ++mt) {
            ap[mt][0] = *(const f16x8*)&pL[((wave * 2 + mt) * 16 + l15) * 76 + quad * 8];
            ap[mt][1] = *(const f16x8*)&pL[((wave * 2 + mt) * 16 + l15) * 76 + 32 + quad * 8];
        }
#pragma unroll
        for (int nt2 = 0; nt2 < 8; ++nt2) {
            const int n2 = nt2 * 16 + l15;
            const f16x8 v0 = *(const f16x8*)&lV[n2 * 64 + ((quad ^ (n2 & 7)) << 3)];
            const f16x8 v1 = *(const f16x8*)&lV[n2 * 64 + (((4 + quad) ^ (n2 & 7)) << 3)];
            accO[0][nt2] = MFMA16(ap[0][0], v0, accO[0][nt2]);
            accO[0][nt2] = MFMA16(ap[0][1], v1, accO[0][nt2]);
            accO[1][nt2] = MFMA16(ap[1][0], v0, accO[1][nt2]);
            accO[1][nt2] = MFMA16(ap[1][1], v1, accO[1][nt2]);
        }
        __syncthreads();
    }

    // ---- l: reduce across the 16 l15 lanes, publish via atomics ----
#pragma unroll
    for (int mt = 0; mt < 2; ++mt)
#pragma unroll
        for (int r2 = 0; r2 < 4; ++r2) {
            float v = l_acc[mt][r2];
            v += __shfl_xor(v, 1);
            v += __shfl_xor(v, 2);
            v += __shfl_xor(v, 4);
            v += __shfl_xor(v, 8);
            if (l15 == 0)
                atomicAdd(&lsum[h * LQ + q0 + mt * 16 + quad * 4 + r2], v);
        }
    // ---- O partial (fp32) ----
    float* Cp = Opart + (long)kc * LQ * CDIM + h * HDIM;
#pragma unroll
    for (int mt = 0; mt < 2; ++mt)
#pragma unroll
        for (int nt2 = 0; nt2 < 8; ++nt2)
#pragma unroll
            for (int rx = 0; rx < 4; ++rx)
                Cp[(long)(q0 + mt * 16 + quad * 4 + rx) * CDIM + nt2 * 16 + l15] =
                    accO[mt][nt2][rx];
}

// ---------------------------------------------------------------------------
// merge: a2[q][c] = (Op0+Op1)[q][c] / lsum[c>>7][q]   (fp16 out)
// ---------------------------------------------------------------------------
__global__ __launch_bounds__(256) void merge_o(
    const float* __restrict__ Op, const float* __restrict__ lsum,
    __half* __restrict__ a2)
{
    const int row = blockIdx.x;
    const int c0  = threadIdx.x * 8;
    const float inv = 1.0f / lsum[(c0 >> 7) * LQ + row];
    const float* p0 = Op + (long)row * CDIM + c0;
    const float* p1 = p0 + (long)LQ * CDIM;
    union { f16x8 v; _Float16 e[8]; } o;
#pragma unroll
    for (int j = 0; j < 8; ++j)
        o.e[j] = (_Float16)((p0[j] + p1[j]) * inv);
    *(f16x8*)&a2[(long)row * 4096 + c0] = o.v;
}

// ---------------------------------------------------------------------------
// ONE prep launch (was cast_all + cast_wo + sw2-transpose + sin_feat +
// lsum-memset = 5 launches). Block ranges select the job.
// ---------------------------------------------------------------------------
__global__ __launch_bounds__(256) void prep_all(
    const float* __restrict__ h2, const float* __restrict__ h0,
    const float* __restrict__ h1, const float* __restrict__ Wq,
    const float* __restrict__ Wk, const float* __restrict__ Wv,
    const float* __restrict__ Wo, const float* __restrict__ sw1,
    const float* __restrict__ sb1, const float* __restrict__ sw2,
    __half* __restrict__ xq, __half* __restrict__ xkv,
    __half* __restrict__ wqh, __half* __restrict__ wkv,
    __half* __restrict__ a2, __half* __restrict__ b2,
    float* __restrict__ lsum)
{
    __shared__ float t[64][65];
    const int blk = blockIdx.x;
    const int tid = threadIdx.x;
    if (blk < 24576) {
        // six fp32->fp16 casts, 4 elem/thread
        const long i = ((long)blk * 256 + tid) << 2;
        const int chunk = (int)(i >> 22);
        const long off = i & 4194303;
        const float* s; __half* d;
        switch (chunk) {
            case 0:  s = h2; d = xq;            break;
            case 1:  s = h0; d = xkv;           break;
            case 2:  s = h1; d = xkv + 4194304; break;
            case 3:  s = Wq; d = wqh;           break;
            case 4:  s = Wk; d = wkv;           break;
            default: s = Wv; d = wkv + 4194304; break;
        }
        const float4 v = *(const float4*)&s[off];
        f16x4 o;
        o[0] = (_Float16)v.x; o[1] = (_Float16)v.y;
        o[2] = (_Float16)v.z; o[3] = (_Float16)v.w;
        *(f16x4*)&d[off] = o;
    } else if (blk < 28672) {
        // Wo -> b2 left half (row o of b2 is 4096 wide)
        const int i = ((blk - 24576) * 256 + tid) << 2;
        const int o = i >> 11, c = i & 2047;
        const float4 v = *(const float4*)&Wo[i];
        f16x4 w4;
        w4[0] = (_Float16)v.x; w4[1] = (_Float16)v.y;
        w4[2] = (_Float16)v.z; w4[3] = (_Float16)v.w;
        *(f16x4*)&b2[((long)o << 12) + c] = w4;
    } else if (blk < 29696) {
        // sw2^T -> b2 right half (64x64 LDS transpose tiles)
        const int lb = blk - 28672;          // 0..1023
        const long r0 = (long)(lb & 31) * 64;
        const long c0 = (long)(lb >> 5) * 64;
        const int tj = tid & 63;
        const int ti = tid >> 6;
#pragma unroll
        for (int it = 0; it < 16; ++it) {
            const int i = it * 4 + ti;
            t[i][tj] = sw2[(r0 + i) * 2048 + c0 + tj];
        }
        __syncthreads();
#pragma unroll
        for (int it = 0; it < 16; ++it) {
            const int i = it * 4 + ti;
            b2[(c0 + i) * 4096 + 2048 + r0 + tj] = __float2half(t[tj][i]);
        }
    } else if (blk < 33792) {
        // sin positional features -> a2 right half
        const int i = ((blk - 29696) * 256 + tid) << 2;
        const int l = i >> 11, c = i & 2047;
        const float coord = -1.0f + (2.0f / 2047.0f) * (float)l;
        const float4 w = *(const float4*)&sw1[c];
        const float4 b = *(const float4*)&sb1[c];
        f16x4 o;
        o[0] = (_Float16)__sinf(30.0f * (coord * w.x + b.x));
        o[1] = (_Float16)__sinf(30.0f * (coord * w.y + b.y));
        o[2] = (_Float16)__sinf(30.0f * (coord * w.z + b.z));
        o[3] = (_Float16)__sinf(30.0f * (coord * w.w + b.w));
        *(f16x4*)&a2[((long)l << 12) + 2048 + c] = o;
    } else {
        // zero lsum (16*2048 floats)
        const int i = ((blk - 33792) * 256 + tid) << 2;
        *(float4*)&lsum[i] = (float4){0.f, 0.f, 0.f, 0.f};
    }
}

__global__ __launch_bounds__(256) void final_norm(
    const float* __restrict__ out2, const float* __restrict__ x,
    const float* __restrict__ sb2, const float* __restrict__ on_w,
    float* __restrict__ y)
{
    const int row = blockIdx.x;
    const float* o0 = out2 + (long)row * CDIM;
    const float* o1 = o0 + (long)LQ * CDIM;   // split-K partial #2
    float4 v[2];
    float ss = 0.f;
#pragma unroll
    for (int i = 0; i < 2; ++i) {
        const int c = threadIdx.x * 4 + i * 1024;
        const float4 a = *(const float4*)&o0[c];
        const float4 b = *(const float4*)&o1[c];
        const float4 s = *(const float4*)&sb2[c];
        float4 tv;
        tv.x = a.x + b.x + s.x; tv.y = a.y + b.y + s.y;
        tv.z = a.z + b.z + s.z; tv.w = a.w + b.w + s.w;
        v[i] = tv;
        ss += tv.x * tv.x + tv.y * tv.y + tv.z * tv.z + tv.w * tv.w;
    }
#pragma unroll
    for (int off = 1; off < 64; off <<= 1) ss += __shfl_xor(ss, off);
    __shared__ float red[4];
    const int lane = threadIdx.x & 63, wv = threadIdx.x >> 6;
    if (lane == 0) red[wv] = ss;
    __syncthreads();
    const float tot = red[0] + red[1] + red[2] + red[3];
    const float rn = rsqrtf(tot * (1.0f / 2048.0f) + 1e-6f);
#pragma unroll
    for (int i = 0; i < 2; ++i) {
        const int c = threadIdx.x * 4 + i * 1024;
        const float4 xr = *(const float4*)&x[(long)row * CDIM + c];
        const float4 wv4 = *(const float4*)&on_w[c];
        float4 o;
        o.x = xr.x + v[i].x * rn * wv4.x;
        o.y = xr.y + v[i].y * rn * wv4.y;
        o.z = xr.z + v[i].z * rn * wv4.z;
        o.w = xr.w + v[i].w * rn * wv4.w;
        *(float4*)&y[(long)row * CDIM + c] = o;
    }
}

// ---------------------------------------------------------------------------
extern "C" void kernel_launch(void* const* d_in, const int* in_sizes, int n_in,
                              void* d_out, int out_size, void* d_ws, size_t ws_size,
                              hipStream_t stream) {
    const float* x    = (const float*)d_in[0];
    const float* h0   = (const float*)d_in[1];
    const float* h1   = (const float*)d_in[2];
    const float* h2   = (const float*)d_in[3];
    const float* Wq   = (const float*)d_in[4];
    const float* Wk   = (const float*)d_in[5];
    const float* Wv   = (const float*)d_in[6];
    const float* Wo   = (const float*)d_in[7];
    const float* qn_w = (const float*)d_in[8];
    const float* kn_w = (const float*)d_in[9];
    const float* on_w = (const float*)d_in[10];
    const float* sw1  = (const float*)d_in[11];
    const float* sb1  = (const float*)d_in[12];
    const float* sw2  = (const float*)d_in[13];
    const float* sb2  = (const float*)d_in[14];
    float* y = (float*)d_out;

    const size_t MB = 1ull << 20;
    char* w = (char*)d_ws;
    __half* xq  = (__half*)(w);             //  8 MB  h2 fp16   [xq;xkv] contiguous
    __half* xkv = (__half*)(w + 8 * MB);    // 16 MB  [h0;h1] fp16
    __half* wqh = (__half*)(w + 24 * MB);   //  8 MB  Wq fp16
    __half* wkv = (__half*)(w + 32 * MB);   // 16 MB  [Wk;Wv] fp16
    __half* qf  = (__half*)(w + 48 * MB);   //  8 MB  Q proj, normed+roped
    __half* kvf = (__half*)(w + 56 * MB);   // 32 MB  K normed (cols 0..2047)
    __half* vT  = (__half*)(w + 88 * MB);   // 16 MB  V transposed (2048x4096)
    __half* a2  = (__half*)(w + 104 * MB);  // 16 MB  [attn_out | sin_feat]
    __half* b2  = (__half*)(w + 120 * MB);  // 16 MB  [Wo | sw2^T]
    float* lsum  = (float*)(w + 136 * MB);  // 128 KB (fresh, zeroed in prep)
    float* Opart = (float*)(w);             // 32 MB  overlays xq/xkv (dead)
    float* out2  = (float*)(w);             // 32 MB  [2] split-K partials,
                                            //        overlays Opart (dead after merge_o)
    (void)in_sizes; (void)n_in; (void)out_size; (void)ws_size;

    // one prep launch: 6 casts + Wo pack + sw2^T + sin features + lsum zero
    prep_all<<<33824, 256, 0, stream>>>(h2, h0, h1, Wq, Wk, Wv, Wo, sw1, sb1,
                                        sw2, xq, xkv, wqh, wkv, a2, b2, lsum);

    // fused: projections + rmsnorm + rope (Q scaled by log2(e)/sqrt(D)) + V^T
    gemm_qkv<<<1280, 256, 0, stream>>>(xq, wqh, wkv, qf, kvf, vT, qn_w, kn_w);

    attn_tile<<<dim3(16, 32), 256, 0, stream>>>(qf, kvf, vT, Opart, lsum);
    merge_o<<<2048, 256, 0, stream>>>(Opart, lsum, a2);

    gemm_sk<<<dim3(16, 16, 2), 256, 0, stream>>>(a2, b2, out2, 4096, 4096, 2048, 2048);
    final_norm<<<2048, 256, 0, stream>>>(out2, x, sb2, on_w, y);
}

// Round 7
// 447.532 us; speedup vs baseline: 1.0433x; 1.0433x over previous
//
#include <hip/hip_runtime.h>
#include <hip/hip_fp16.h>

// Problem constants: B=1, L=2048, C=2048, H=16, D=128, keys = 2L = 4096
#define LQ 2048
#define CDIM 2048
#define NHEAD 16
#define HDIM 128
#define LKEY 4096

typedef _Float16 f16x8 __attribute__((ext_vector_type(8)));
typedef _Float16 f16x4 __attribute__((ext_vector_type(4)));
typedef float f32x4 __attribute__((ext_vector_type(4)));

#define GLOAD_LDS16(g, s) __builtin_amdgcn_global_load_lds( \
    (const __attribute__((address_space(1))) void*)(g),     \
    (__attribute__((address_space(3))) void*)(s), 16, 0, 0)

#define MFMA16(a, b, c) __builtin_amdgcn_mfma_f32_16x16x32_f16(a, b, c, 0, 0, 0)

__device__ __forceinline__ void storeC(float* p, float v) { *p = v; }
__device__ __forceinline__ void storeC(__half* p, float v) { *p = __float2half(v); }

// ---------------------------------------------------------------------------
// Shared GEMM body: C-tile = A[128bmA:+128, :K] * B[128bn:+128, :K]^T
// 128x128 tile, BK=64, 4 waves, 4x4 acc/wave, global_load_lds staging.
// MODE 0: plain store. MODE 1: fused rmsnorm+rope epilogue (fp16).
// MODE 2: transposed store into vTo[d][key].
// ---------------------------------------------------------------------------
template <int MODE, typename OutT>
__device__ __forceinline__ void gemm_body(
    __half* smem,
    const __half* __restrict__ A, const __half* __restrict__ B,
    OutT* __restrict__ C, int lda, int ldb, int ldc, int K,
    int bmA, int bmC, int bn,
    const float* __restrict__ wgt, int kmode, float oscale,
    __half* __restrict__ vTo)
{
    __half* lA = smem;
    __half* lB = smem + 8192;
    const int tid  = threadIdx.x;
    const int lane = tid & 63;
    const int wave = tid >> 6;
    const int r = tid >> 3;     // 0..31: row within 32-row staging slab
    const int g = tid & 7;      // 8-elem col group
    const __half* gA = A + (long)(bmA * 128 + r) * lda + ((g ^ (r & 7)) << 3);
    const __half* gB = B + (long)(bn * 128 + r) * ldb + ((g ^ (r & 7)) << 3);
    __half* lAp = lA + tid * 8;
    __half* lBp = lB + tid * 8;
    const int wr = (wave & 1) << 6;
    const int wc = (wave >> 1) << 6;
    const int l15 = lane & 15, quad = lane >> 4;

    f32x4 acc[4][4] = {};

    for (int kt = 0; kt < K; kt += 64) {
#pragma unroll
        for (int i = 0; i < 4; ++i) {
            GLOAD_LDS16(gA + (long)i * 32 * lda, lAp + i * 2048);
            GLOAD_LDS16(gB + (long)i * 32 * ldb, lBp + i * 2048);
        }
        gA += 64; gB += 64;
        __syncthreads();
#pragma unroll
        for (int kk = 0; kk < 2; ++kk) {
            f16x8 af[4], bfr[4];
#pragma unroll
            for (int mi = 0; mi < 4; ++mi) {
                const int m = wr + mi * 16 + l15;
                const int kg = kk * 4 + quad;
                af[mi] = *(const f16x8*)&lA[m * 64 + ((kg ^ (m & 7)) << 3)];
            }
#pragma unroll
            for (int ni = 0; ni < 4; ++ni) {
                const int n = wc + ni * 16 + l15;
                const int kg = kk * 4 + quad;
                bfr[ni] = *(const f16x8*)&lB[n * 64 + ((kg ^ (n & 7)) << 3)];
            }
#pragma unroll
            for (int mi = 0; mi < 4; ++mi)
#pragma unroll
                for (int ni = 0; ni < 4; ++ni)
                    acc[mi][ni] = MFMA16(af[mi], bfr[ni], acc[mi][ni]);
        }
        __syncthreads();
    }

    if constexpr (MODE == 0) {
        const int row0 = bmC * 128 + wr + quad * 4;
        const int col0 = bn * 128 + wc + l15;
#pragma unroll
        for (int mi = 0; mi < 4; ++mi)
#pragma unroll
            for (int ni = 0; ni < 4; ++ni)
#pragma unroll
                for (int rx = 0; rx < 4; ++rx)
                    storeC(&C[(long)(row0 + mi * 16 + rx) * ldc + col0 + ni * 16],
                           acc[mi][ni][rx]);
    } else if constexpr (MODE == 2) {
        // transposed store: vTo[d][key], d = tile col, key = tile row
#pragma unroll
        for (int mi = 0; mi < 4; ++mi)
#pragma unroll
            for (int ni = 0; ni < 4; ++ni)
#pragma unroll
                for (int rx = 0; rx < 4; ++rx) {
                    const int  d   = (bn - 16) * 128 + wc + ni * 16 + l15;
                    const long key = (long)bmC * 128 + wr + mi * 16 + quad * 4 + rx;
                    vTo[(long)d * LKEY + key] = __float2half(acc[mi][ni][rx]);
                }
    } else {
        // MODE 1: rmsnorm + rope fused. Tile cols = one head's D=128.
        __half* sT = smem;   // [128][136] fp16, aliases lA/lB (dead)
#pragma unroll
        for (int mi = 0; mi < 4; ++mi)
#pragma unroll
            for (int ni = 0; ni < 4; ++ni)
#pragma unroll
                for (int rx = 0; rx < 4; ++rx)
                    sT[(wr + mi * 16 + quad * 4 + rx) * 136 + wc + ni * 16 + l15] =
                        (_Float16)acc[mi][ni][rx];
        __syncthreads();
        const int row = (wave << 5) + (lane >> 1);   // 32 rows/wave
        const int c0  = (lane & 1) << 5;             // 0 or 32
        const __half* rp = sT + row * 136;
        f16x8 L[4], Hh[4];
#pragma unroll
        for (int j8 = 0; j8 < 4; ++j8) {
            L[j8]  = *(const f16x8*)&rp[c0 + j8 * 8];
            Hh[j8] = *(const f16x8*)&rp[c0 + 64 + j8 * 8];
        }
        float ss = 0.f;
#pragma unroll
        for (int j8 = 0; j8 < 4; ++j8)
#pragma unroll
            for (int e = 0; e < 8; ++e) {
                const float a = (float)L[j8][e], b = (float)Hh[j8][e];
                ss += a * a + b * b;
            }
        ss += __shfl_xor(ss, 1);                     // lane-pair -> full 128
        const float rn = rsqrtf(ss * (1.0f / 128.0f) + 1e-6f);
        const long grow = (long)bmC * 128 + row;
        const int depth = kmode ? (grow < 2048 ? 0 : 1) : 2;
        union { f16x8 v; _Float16 e[8]; } o1[4], o2[4];
#pragma unroll
        for (int j8 = 0; j8 < 4; ++j8)
#pragma unroll
            for (int e = 0; e < 8; ++e) {
                const int d = c0 + j8 * 8 + e;
                const float x1 = (float)L[j8][e]  * rn * wgt[d];
                const float x2 = (float)Hh[j8][e] * rn * wgt[d + 64];
                const float ang = (float)depth *
                    exp2f(-(float)d * 0.20762050593045702f);
                float sn, cs;
                __sincosf(ang, &sn, &cs);
                o1[j8].e[e] = (_Float16)((x1 * cs - x2 * sn) * oscale);
                o2[j8].e[e] = (_Float16)((x1 * sn + x2 * cs) * oscale);
            }
        __half* op = (__half*)C + grow * ldc + bn * 128;
#pragma unroll
        for (int j8 = 0; j8 < 4; ++j8) {
            *(f16x8*)&op[c0 + j8 * 8]      = o1[j8].v;
            *(f16x8*)&op[c0 + 64 + j8 * 8] = o2[j8].v;
        }
    }
}

// ---------------------------------------------------------------------------
// Fused Q+KV projection GEMM (1280 blocks). __launch_bounds__(256,2) is the
// empirically-tuned config: (256,4) did NOT raise measured occupancy (28% vs
// 30%) but broke L2 write-combining on the epilogue stores (WRITE_SIZE
// 41->55MB, dur 101->138us). Do not "fix" the occupancy again.
// ---------------------------------------------------------------------------
__global__ __launch_bounds__(256, 2) void gemm_qkv(
    const __half* __restrict__ A, const __half* __restrict__ Bq,
    const __half* __restrict__ Bkv, __half* __restrict__ Cq,
    __half* __restrict__ Ckv, __half* __restrict__ vT,
    const float* __restrict__ qn_w, const float* __restrict__ kn_w)
{
    __shared__ __align__(16) __half smem[17408];
    const int lin = blockIdx.x;
    if (lin < 1024) {
        const int bm = lin & 31, bn = lin >> 5;
        if (bn < 16)
            gemm_body<1, __half>(smem, A, Bkv, Ckv, 2048, 2048, 4096, 2048,
                                 bm + 16, bm, bn, kn_w, 1, 1.0f, nullptr);
        else
            gemm_body<2, __half>(smem, A, Bkv, Ckv, 2048, 2048, 4096, 2048,
                                 bm + 16, bm, bn, nullptr, 0, 1.0f, vT);
    } else {
        const int l2 = lin - 1024;
        const int bm = l2 & 15, bn = l2 >> 4;
        gemm_body<1, __half>(smem, A, Bq, Cq, 2048, 2048, 2048, 2048,
                             bm, bm, bn, qn_w, 0, 0.12751743f, nullptr);
    }
}

// ---------------------------------------------------------------------------
// Split-K x2 final GEMM: grid (16,16,2) = 512 blocks.
// ---------------------------------------------------------------------------
__global__ __launch_bounds__(256, 4) void gemm_sk(
    const __half* __restrict__ A, const __half* __restrict__ B,
    float* __restrict__ C, int lda, int ldb, int ldc, int Khalf)
{
    __shared__ __align__(16) __half smem[16384];
    const int z = blockIdx.z;
    gemm_body<0, float>(smem, A + z * Khalf, B + z * Khalf,
                        C + (long)z * LQ * CDIM,
                        lda, ldb, ldc, Khalf, blockIdx.x, blockIdx.x, blockIdx.y,
                        nullptr, 0, 1.0f, nullptr);
}

// ---------------------------------------------------------------------------
// Fused attention tile kernel (max-free softmax, log2-domain scores).
// Best-measured structure (v1/v5), unchanged. Grid (16, 32 = head*2+kc).
// ---------------------------------------------------------------------------
__global__ __launch_bounds__(256, 2) void attn_tile(
    const __half* __restrict__ Qf,  // [2048][2048] normed+roped, log2-scaled
    const __half* __restrict__ Kf,  // kvf [4096][4096]; K in cols 0..2047
    const __half* __restrict__ Vt,  // [2048][4096]  Vt[h*128+d][key]
    float* __restrict__ Opart,      // [2][2048][2048]
    float* __restrict__ lsum)       // [16][2048]
{
    __shared__ __align__(16) __half lK[64 * 128];   // 16 KB
    __shared__ __align__(16) __half lV[128 * 64];   // 16 KB
    __shared__ __align__(16) __half pL[4 * 2 * 16 * 76];  // 19 KB

    const int tid  = threadIdx.x;
    const int lane = tid & 63;
    const int wave = tid >> 6;
    const int l15  = lane & 15;
    const int quad = lane >> 4;
    const int h  = blockIdx.y >> 1;
    const int kc = blockIdx.y & 1;
    const int q0 = blockIdx.x * 128 + wave * 32;   // this wave's 32 q-rows

    // Q A-fragments: A[m=l15][k=ks*32+quad*8+j]
    f16x8 aq[2][4];
#pragma unroll
    for (int mt = 0; mt < 2; ++mt)
#pragma unroll
        for (int ks = 0; ks < 4; ++ks)
            aq[mt][ks] = *(const f16x8*)&Qf[(long)(q0 + mt * 16 + l15) * CDIM +
                                            h * HDIM + ks * 32 + quad * 8];

    // staging pointers. LDS[r][g] = global[r][g ^ (r & mask)] (XOR swizzle in
    // the SOURCE address; LDS dest is wave-uniform base + lane*16).
    const int rK = tid >> 4;          // K row 0..15 (+16/issue)
    const int gK = tid & 15;          // 16 groups of 8 halves
    const __half* srcK = Kf + (long)(kc * 2048 + rK) * 4096 + h * HDIM +
                         ((gK ^ (rK & 15)) << 3);
    const int rV = tid >> 3;          // V row (d) 0..31 (+32/issue)
    const int gV = tid & 7;           // 8 groups of 8 halves
    const __half* srcV = Vt + (long)(h * HDIM + rV) * (long)LKEY + kc * 2048 +
                         ((gV ^ (rV & 7)) << 3);
    __half* dstK = lK + tid * 8;
    __half* dstV = lV + tid * 8;

    f32x4 accO[2][8] = {};
    f32x4 l_acc[2] = {};

    for (int st = 0; st < 32; ++st) {
#pragma unroll
        for (int i = 0; i < 4; ++i) {
            GLOAD_LDS16(srcK + (long)(st * 64 + i * 16) * 4096, dstK + i * 2048);
            GLOAD_LDS16(srcV + (long)i * 32 * LKEY + st * 64, dstV + i * 2048);
        }
        __syncthreads();
        // ---- QK^T (acc init -10 folds the exp2 bias) ----
        f32x4 s[2][4];
#pragma unroll
        for (int mt = 0; mt < 2; ++mt)
#pragma unroll
            for (int nt = 0; nt < 4; ++nt)
                s[mt][nt] = (f32x4){-10.f, -10.f, -10.f, -10.f};
#pragma unroll
        for (int nt = 0; nt < 4; ++nt) {
            const int n = nt * 16 + l15;
#pragma unroll
            for (int ks = 0; ks < 4; ++ks) {
                const f16x8 kf = *(const f16x8*)
                    &lK[n * 128 + (((ks * 4 + quad) ^ (n & 15)) << 3)];
                s[0][nt] = MFMA16(aq[0][ks], kf, s[0][nt]);
                s[1][nt] = MFMA16(aq[1][ks], kf, s[1][nt]);
            }
        }
        // ---- P = exp2(s), accumulate l, stage P (per-wave slab) ----
#pragma unroll
        for (int mt = 0; mt < 2; ++mt)
#pragma unroll
            for (int nt = 0; nt < 4; ++nt)
#pragma unroll
                for (int r2 = 0; r2 < 4; ++r2) {
                    const float p = __builtin_amdgcn_exp2f(s[mt][nt][r2]);
                    l_acc[mt][r2] += p;
                    pL[((wave * 2 + mt) * 16 + quad * 4 + r2) * 76 +
                       nt * 16 + l15] = __float2half(p);
                }
        // ---- PV ----
        f16x8 ap[2][2];
#pragma unroll
        for (int mt = 0; mt < 2; ++mt) {
            ap[mt][0] = *(const f16x8*)&pL[((wave * 2 + mt) * 16 + l15) * 76 + quad * 8];
            ap[mt][1] = *(const f16x8*)&pL[((wave * 2 + mt) * 16 + l15) * 76 + 32 + quad * 8];
        }
#pragma unroll
        for (int nt2 = 0; nt2 < 8; ++nt2) {
            const int n2 = nt2 * 16 + l15;
            const f16x8 v0 = *(const f16x8*)&lV[n2 * 64 + ((quad ^ (n2 & 7)) << 3)];
            const f16x8 v1 = *(const f16x8*)&lV[n2 * 64 + (((4 + quad) ^ (n2 & 7)) << 3)];
            accO[0][nt2] = MFMA16(ap[0][0], v0, accO[0][nt2]);
            accO[0][nt2] = MFMA16(ap[0][1], v1, accO[0][nt2]);
            accO[1][nt2] = MFMA16(ap[1][0], v0, accO[1][nt2]);
            accO[1][nt2] = MFMA16(ap[1][1], v1, accO[1][nt2]);
        }
        __syncthreads();
    }

    // ---- l: reduce across the 16 l15 lanes, publish via atomics ----
#pragma unroll
    for (int mt = 0; mt < 2; ++mt)
#pragma unroll
        for (int r2 = 0; r2 < 4; ++r2) {
            float v = l_acc[mt][r2];
            v += __shfl_xor(v, 1);
            v += __shfl_xor(v, 2);
            v += __shfl_xor(v, 4);
            v += __shfl_xor(v, 8);
            if (l15 == 0)
                atomicAdd(&lsum[h * LQ + q0 + mt * 16 + quad * 4 + r2], v);
        }
    // ---- O partial (fp32) ----
    float* Cp = Opart + (long)kc * LQ * CDIM + h * HDIM;
#pragma unroll
    for (int mt = 0; mt < 2; ++mt)
#pragma unroll
        for (int nt2 = 0; nt2 < 8; ++nt2)
#pragma unroll
            for (int rx = 0; rx < 4; ++rx)
                Cp[(long)(q0 + mt * 16 + quad * 4 + rx) * CDIM + nt2 * 16 + l15] =
                    accO[mt][nt2][rx];
}

// ---------------------------------------------------------------------------
// merge: a2[q][c] = (Op0+Op1)[q][c] / lsum[c>>7][q]   (fp16 out)
// ---------------------------------------------------------------------------
__global__ __launch_bounds__(256) void merge_o(
    const float* __restrict__ Op, const float* __restrict__ lsum,
    __half* __restrict__ a2)
{
    const int row = blockIdx.x;
    const int c0  = threadIdx.x * 8;
    const float inv = 1.0f / lsum[(c0 >> 7) * LQ + row];
    const float* p0 = Op + (long)row * CDIM + c0;
    const float* p1 = p0 + (long)LQ * CDIM;
    union { f16x8 v; _Float16 e[8]; } o;
#pragma unroll
    for (int j = 0; j < 8; ++j)
        o.e[j] = (_Float16)((p0[j] + p1[j]) * inv);
    *(f16x8*)&a2[(long)row * 4096 + c0] = o.v;
}

// ---------------------------------------------------------------------------
// ONE prep launch: 6 casts + Wo pack + sw2^T + sin features + lsum zero.
// ---------------------------------------------------------------------------
__global__ __launch_bounds__(256) void prep_all(
    const float* __restrict__ h2, const float* __restrict__ h0,
    const float* __restrict__ h1, const float* __restrict__ Wq,
    const float* __restrict__ Wk, const float* __restrict__ Wv,
    const float* __restrict__ Wo, const float* __restrict__ sw1,
    const float* __restrict__ sb1, const float* __restrict__ sw2,
    __half* __restrict__ xq, __half* __restrict__ xkv,
    __half* __restrict__ wqh, __half* __restrict__ wkv,
    __half* __restrict__ a2, __half* __restrict__ b2,
    float* __restrict__ lsum)
{
    __shared__ float t[64][65];
    const int blk = blockIdx.x;
    const int tid = threadIdx.x;
    if (blk < 24576) {
        // six fp32->fp16 casts, 4 elem/thread
        const long i = ((long)blk * 256 + tid) << 2;
        const int chunk = (int)(i >> 22);
        const long off = i & 4194303;
        const float* s; __half* d;
        switch (chunk) {
            case 0:  s = h2; d = xq;            break;
            case 1:  s = h0; d = xkv;           break;
            case 2:  s = h1; d = xkv + 4194304; break;
            case 3:  s = Wq; d = wqh;           break;
            case 4:  s = Wk; d = wkv;           break;
            default: s = Wv; d = wkv + 4194304; break;
        }
        const float4 v = *(const float4*)&s[off];
        f16x4 o;
        o[0] = (_Float16)v.x; o[1] = (_Float16)v.y;
        o[2] = (_Float16)v.z; o[3] = (_Float16)v.w;
        *(f16x4*)&d[off] = o;
    } else if (blk < 28672) {
        // Wo -> b2 left half (row o of b2 is 4096 wide)
        const int i = ((blk - 24576) * 256 + tid) << 2;
        const int o = i >> 11, c = i & 2047;
        const float4 v = *(const float4*)&Wo[i];
        f16x4 w4;
        w4[0] = (_Float16)v.x; w4[1] = (_Float16)v.y;
        w4[2] = (_Float16)v.z; w4[3] = (_Float16)v.w;
        *(f16x4*)&b2[((long)o << 12) + c] = w4;
    } else if (blk < 29696) {
        // sw2^T -> b2 right half (64x64 LDS transpose tiles)
        const int lb = blk - 28672;          // 0..1023
        const long r0 = (long)(lb & 31) * 64;
        const long c0 = (long)(lb >> 5) * 64;
        const int tj = tid & 63;
        const int ti = tid >> 6;
#pragma unroll
        for (int it = 0; it < 16; ++it) {
            const int i = it * 4 + ti;
            t[i][tj] = sw2[(r0 + i) * 2048 + c0 + tj];
        }
        __syncthreads();
#pragma unroll
        for (int it = 0; it < 16; ++it) {
            const int i = it * 4 + ti;
            b2[(c0 + i) * 4096 + 2048 + r0 + tj] = __float2half(t[tj][i]);
        }
    } else if (blk < 33792) {
        // sin positional features -> a2 right half
        const int i = ((blk - 29696) * 256 + tid) << 2;
        const int l = i >> 11, c = i & 2047;
        const float coord = -1.0f + (2.0f / 2047.0f) * (float)l;
        const float4 w = *(const float4*)&sw1[c];
        const float4 b = *(const float4*)&sb1[c];
        f16x4 o;
        o[0] = (_Float16)__sinf(30.0f * (coord * w.x + b.x));
        o[1] = (_Float16)__sinf(30.0f * (coord * w.y + b.y));
        o[2] = (_Float16)__sinf(30.0f * (coord * w.z + b.z));
        o[3] = (_Float16)__sinf(30.0f * (coord * w.w + b.w));
        *(f16x4*)&a2[((long)l << 12) + 2048 + c] = o;
    } else {
        // zero lsum (16*2048 floats)
        const int i = ((blk - 33792) * 256 + tid) << 2;
        *(float4*)&lsum[i] = (float4){0.f, 0.f, 0.f, 0.f};
    }
}

__global__ __launch_bounds__(256) void final_norm(
    const float* __restrict__ out2, const float* __restrict__ x,
    const float* __restrict__ sb2, const float* __restrict__ on_w,
    float* __restrict__ y)
{
    const int row = blockIdx.x;
    const float* o0 = out2 + (long)row * CDIM;
    const float* o1 = o0 + (long)LQ * CDIM;   // split-K partial #2
    float4 v[2];
    float ss = 0.f;
#pragma unroll
    for (int i = 0; i < 2; ++i) {
        const int c = threadIdx.x * 4 + i * 1024;
        const float4 a = *(const float4*)&o0[c];
        const float4 b = *(const float4*)&o1[c];
        const float4 s = *(const float4*)&sb2[c];
        float4 tv;
        tv.x = a.x + b.x + s.x; tv.y = a.y + b.y + s.y;
        tv.z = a.z + b.z + s.z; tv.w = a.w + b.w + s.w;
        v[i] = tv;
        ss += tv.x * tv.x + tv.y * tv.y + tv.z * tv.z + tv.w * tv.w;
    }
#pragma unroll
    for (int off = 1; off < 64; off <<= 1) ss += __shfl_xor(ss, off);
    __shared__ float red[4];
    const int lane = threadIdx.x & 63, wv = threadIdx.x >> 6;
    if (lane == 0) red[wv] = ss;
    __syncthreads();
    const float tot = red[0] + red[1] + red[2] + red[3];
    const float rn = rsqrtf(tot * (1.0f / 2048.0f) + 1e-6f);
#pragma unroll
    for (int i = 0; i < 2; ++i) {
        const int c = threadIdx.x * 4 + i * 1024;
        const float4 xr = *(const float4*)&x[(long)row * CDIM + c];
        const float4 wv4 = *(const float4*)&on_w[c];
        float4 o;
        o.x = xr.x + v[i].x * rn * wv4.x;
        o.y = xr.y + v[i].y * rn * wv4.y;
        o.z = xr.z + v[i].z * rn * wv4.z;
        o.w = xr.w + v[i].w * rn * wv4.w;
        *(float4*)&y[(long)row * CDIM + c] = o;
    }
}

// ---------------------------------------------------------------------------
extern "C" void kernel_launch(void* const* d_in, const int* in_sizes, int n_in,
                              void* d_out, int out_size, void* d_ws, size_t ws_size,
                              hipStream_t stream) {
    const float* x    = (const float*)d_in[0];
    const float* h0   = (const float*)d_in[1];
    const float* h1   = (const float*)d_in[2];
    const float* h2   = (const float*)d_in[3];
    const float* Wq   = (const float*)d_in[4];
    const float* Wk   = (const float*)d_in[5];
    const float* Wv   = (const float*)d_in[6];
    const float* Wo   = (const float*)d_in[7];
    const float* qn_w = (const float*)d_in[8];
    const float* kn_w = (const float*)d_in[9];
    const float* on_w = (const float*)d_in[10];
    const float* sw1  = (const float*)d_in[11];
    const float* sb1  = (const float*)d_in[12];
    const float* sw2  = (const float*)d_in[13];
    const float* sb2  = (const float*)d_in[14];
    float* y = (float*)d_out;

    const size_t MB = 1ull << 20;
    char* w = (char*)d_ws;
    __half* xq  = (__half*)(w);             //  8 MB  h2 fp16   [xq;xkv] contiguous
    __half* xkv = (__half*)(w + 8 * MB);    // 16 MB  [h0;h1] fp16
    __half* wqh = (__half*)(w + 24 * MB);   //  8 MB  Wq fp16
    __half* wkv = (__half*)(w + 32 * MB);   // 16 MB  [Wk;Wv] fp16
    __half* qf  = (__half*)(w + 48 * MB);   //  8 MB  Q proj, normed+roped
    __half* kvf = (__half*)(w + 56 * MB);   // 32 MB  K normed (cols 0..2047)
    __half* vT  = (__half*)(w + 88 * MB);   // 16 MB  V transposed (2048x4096)
    __half* a2  = (__half*)(w + 104 * MB);  // 16 MB  [attn_out | sin_feat]
    __half* b2  = (__half*)(w + 120 * MB);  // 16 MB  [Wo | sw2^T]
    float* lsum  = (float*)(w + 136 * MB);  // 128 KB (fresh, zeroed in prep)
    float* Opart = (float*)(w);             // 32 MB  overlays xq/xkv (dead)
    float* out2  = (float*)(w);             // 32 MB  [2] split-K partials,
                                            //        overlays Opart (dead after merge_o)
    (void)in_sizes; (void)n_in; (void)out_size; (void)ws_size;

    // one prep launch: 6 casts + Wo pack + sw2^T + sin features + lsum zero
    prep_all<<<33824, 256, 0, stream>>>(h2, h0, h1, Wq, Wk, Wv, Wo, sw1, sb1,
                                        sw2, xq, xkv, wqh, wkv, a2, b2, lsum);

    // fused: projections + rmsnorm + rope (Q scaled by log2(e)/sqrt(D)) + V^T
    gemm_qkv<<<1280, 256, 0, stream>>>(xq, wqh, wkv, qf, kvf, vT, qn_w, kn_w);

    attn_tile<<<dim3(16, 32), 256, 0, stream>>>(qf, kvf, vT, Opart, lsum);
    merge_o<<<2048, 256, 0, stream>>>(Opart, lsum, a2);

    gemm_sk<<<dim3(16, 16, 2), 256, 0, stream>>>(a2, b2, out2, 4096, 4096, 2048, 2048);
    final_norm<<<2048, 256, 0, stream>>>(out2, x, sb2, on_w, y);
}

// Round 8
// 445.871 us; speedup vs baseline: 1.0472x; 1.0037x over previous
//
#include <hip/hip_runtime.h>
#include <hip/hip_fp16.h>

// Problem constants: B=1, L=2048, C=2048, H=16, D=128, keys = 2L = 4096
#define LQ 2048
#define CDIM 2048
#define NHEAD 16
#define HDIM 128
#define LKEY 4096

typedef _Float16 f16x8 __attribute__((ext_vector_type(8)));
typedef _Float16 f16x4 __attribute__((ext_vector_type(4)));
typedef float f32x4 __attribute__((ext_vector_type(4)));

#define GLOAD_LDS16(g, s) __builtin_amdgcn_global_load_lds( \
    (const __attribute__((address_space(1))) void*)(g),     \
    (__attribute__((address_space(3))) void*)(s), 16, 0, 0)

#define MFMA16(a, b, c) __builtin_amdgcn_mfma_f32_16x16x32_f16(a, b, c, 0, 0, 0)

__device__ __forceinline__ void storeC(float* p, float v) { *p = v; }
__device__ __forceinline__ void storeC(__half* p, float v) { *p = __float2half(v); }

// ---------------------------------------------------------------------------
// Shared GEMM body: C-tile = A[128bmA:+128, :K] * B[128bn:+128, :K]^T
// 128x128 tile, BK=64, 4 waves, 4x4 acc/wave, global_load_lds staging.
// MODE 0: plain store. MODE 1: fused rmsnorm+rope epilogue (fp16).
// MODE 2: transposed store into vTo[d][key].
// ---------------------------------------------------------------------------
template <int MODE, typename OutT>
__device__ __forceinline__ void gemm_body(
    __half* smem,
    const __half* __restrict__ A, const __half* __restrict__ B,
    OutT* __restrict__ C, int lda, int ldb, int ldc, int K,
    int bmA, int bmC, int bn,
    const float* __restrict__ wgt, int kmode, float oscale,
    __half* __restrict__ vTo)
{
    __half* lA = smem;
    __half* lB = smem + 8192;
    const int tid  = threadIdx.x;
    const int lane = tid & 63;
    const int wave = tid >> 6;
    const int r = tid >> 3;     // 0..31: row within 32-row staging slab
    const int g = tid & 7;      // 8-elem col group
    const __half* gA = A + (long)(bmA * 128 + r) * lda + ((g ^ (r & 7)) << 3);
    const __half* gB = B + (long)(bn * 128 + r) * ldb + ((g ^ (r & 7)) << 3);
    __half* lAp = lA + tid * 8;
    __half* lBp = lB + tid * 8;
    const int wr = (wave & 1) << 6;
    const int wc = (wave >> 1) << 6;
    const int l15 = lane & 15, quad = lane >> 4;

    f32x4 acc[4][4] = {};

    for (int kt = 0; kt < K; kt += 64) {
#pragma unroll
        for (int i = 0; i < 4; ++i) {
            GLOAD_LDS16(gA + (long)i * 32 * lda, lAp + i * 2048);
            GLOAD_LDS16(gB + (long)i * 32 * ldb, lBp + i * 2048);
        }
        gA += 64; gB += 64;
        __syncthreads();
#pragma unroll
        for (int kk = 0; kk < 2; ++kk) {
            f16x8 af[4], bfr[4];
#pragma unroll
            for (int mi = 0; mi < 4; ++mi) {
                const int m = wr + mi * 16 + l15;
                const int kg = kk * 4 + quad;
                af[mi] = *(const f16x8*)&lA[m * 64 + ((kg ^ (m & 7)) << 3)];
            }
#pragma unroll
            for (int ni = 0; ni < 4; ++ni) {
                const int n = wc + ni * 16 + l15;
                const int kg = kk * 4 + quad;
                bfr[ni] = *(const f16x8*)&lB[n * 64 + ((kg ^ (n & 7)) << 3)];
            }
#pragma unroll
            for (int mi = 0; mi < 4; ++mi)
#pragma unroll
                for (int ni = 0; ni < 4; ++ni)
                    acc[mi][ni] = MFMA16(af[mi], bfr[ni], acc[mi][ni]);
        }
        __syncthreads();
    }

    if constexpr (MODE == 0) {
        const int row0 = bmC * 128 + wr + quad * 4;
        const int col0 = bn * 128 + wc + l15;
#pragma unroll
        for (int mi = 0; mi < 4; ++mi)
#pragma unroll
            for (int ni = 0; ni < 4; ++ni)
#pragma unroll
                for (int rx = 0; rx < 4; ++rx)
                    storeC(&C[(long)(row0 + mi * 16 + rx) * ldc + col0 + ni * 16],
                           acc[mi][ni][rx]);
    } else if constexpr (MODE == 2) {
        // transposed store: vTo[d][key], d = tile col, key = tile row
#pragma unroll
        for (int mi = 0; mi < 4; ++mi)
#pragma unroll
            for (int ni = 0; ni < 4; ++ni)
#pragma unroll
                for (int rx = 0; rx < 4; ++rx) {
                    const int  d   = (bn - 16) * 128 + wc + ni * 16 + l15;
                    const long key = (long)bmC * 128 + wr + mi * 16 + quad * 4 + rx;
                    vTo[(long)d * LKEY + key] = __float2half(acc[mi][ni][rx]);
                }
    } else {
        // MODE 1: rmsnorm + rope fused. Tile cols = one head's D=128.
        __half* sT = smem;   // [128][136] fp16, aliases lA/lB (dead)
#pragma unroll
        for (int mi = 0; mi < 4; ++mi)
#pragma unroll
            for (int ni = 0; ni < 4; ++ni)
#pragma unroll
                for (int rx = 0; rx < 4; ++rx)
                    sT[(wr + mi * 16 + quad * 4 + rx) * 136 + wc + ni * 16 + l15] =
                        (_Float16)acc[mi][ni][rx];
        __syncthreads();
        const int row = (wave << 5) + (lane >> 1);   // 32 rows/wave
        const int c0  = (lane & 1) << 5;             // 0 or 32
        const __half* rp = sT + row * 136;
        f16x8 L[4], Hh[4];
#pragma unroll
        for (int j8 = 0; j8 < 4; ++j8) {
            L[j8]  = *(const f16x8*)&rp[c0 + j8 * 8];
            Hh[j8] = *(const f16x8*)&rp[c0 + 64 + j8 * 8];
        }
        float ss = 0.f;
#pragma unroll
        for (int j8 = 0; j8 < 4; ++j8)
#pragma unroll
            for (int e = 0; e < 8; ++e) {
                const float a = (float)L[j8][e], b = (float)Hh[j8][e];
                ss += a * a + b * b;
            }
        ss += __shfl_xor(ss, 1);                     // lane-pair -> full 128
        const float rn = rsqrtf(ss * (1.0f / 128.0f) + 1e-6f);
        const long grow = (long)bmC * 128 + row;
        const int depth = kmode ? (grow < 2048 ? 0 : 1) : 2;
        union { f16x8 v; _Float16 e[8]; } o1[4], o2[4];
#pragma unroll
        for (int j8 = 0; j8 < 4; ++j8)
#pragma unroll
            for (int e = 0; e < 8; ++e) {
                const int d = c0 + j8 * 8 + e;
                const float x1 = (float)L[j8][e]  * rn * wgt[d];
                const float x2 = (float)Hh[j8][e] * rn * wgt[d + 64];
                const float ang = (float)depth *
                    exp2f(-(float)d * 0.20762050593045702f);
                float sn, cs;
                __sincosf(ang, &sn, &cs);
                o1[j8].e[e] = (_Float16)((x1 * cs - x2 * sn) * oscale);
                o2[j8].e[e] = (_Float16)((x1 * sn + x2 * cs) * oscale);
            }
        __half* op = (__half*)C + grow * ldc + bn * 128;
#pragma unroll
        for (int j8 = 0; j8 < 4; ++j8) {
            *(f16x8*)&op[c0 + j8 * 8]      = o1[j8].v;
            *(f16x8*)&op[c0 + 64 + j8 * 8] = o2[j8].v;
        }
    }
}

// ---------------------------------------------------------------------------
// Fused Q+KV projection GEMM (1280 blocks). __launch_bounds__(256,2) is the
// empirically-tuned config: (256,4) did NOT raise measured occupancy but
// broke L2 write-combining on the epilogue stores (WRITE_SIZE 41->55MB,
// dur 101->138us). Do not "fix" the occupancy again.
// ---------------------------------------------------------------------------
__global__ __launch_bounds__(256, 2) void gemm_qkv(
    const __half* __restrict__ A, const __half* __restrict__ Bq,
    const __half* __restrict__ Bkv, __half* __restrict__ Cq,
    __half* __restrict__ Ckv, __half* __restrict__ vT,
    const float* __restrict__ qn_w, const float* __restrict__ kn_w)
{
    __shared__ __align__(16) __half smem[17408];
    const int lin = blockIdx.x;
    if (lin < 1024) {
        const int bm = lin & 31, bn = lin >> 5;
        if (bn < 16)
            gemm_body<1, __half>(smem, A, Bkv, Ckv, 2048, 2048, 4096, 2048,
                                 bm + 16, bm, bn, kn_w, 1, 1.0f, nullptr);
        else
            gemm_body<2, __half>(smem, A, Bkv, Ckv, 2048, 2048, 4096, 2048,
                                 bm + 16, bm, bn, nullptr, 0, 1.0f, vT);
    } else {
        const int l2 = lin - 1024;
        const int bm = l2 & 15, bn = l2 >> 4;
        gemm_body<1, __half>(smem, A, Bq, Cq, 2048, 2048, 2048, 2048,
                             bm, bm, bn, qn_w, 0, 0.12751743f, nullptr);
    }
}

// ---------------------------------------------------------------------------
// Split-K x2 final GEMM: grid (16,16,2) = 512 blocks. (256,2): the MODE-0
// epilogue is 64 scalar fp32 stores/thread -- the same scatter pattern that
// regressed gemm_qkv 36% at (256,4) via broken L2 write-combining.
// ---------------------------------------------------------------------------
__global__ __launch_bounds__(256, 2) void gemm_sk(
    const __half* __restrict__ A, const __half* __restrict__ B,
    float* __restrict__ C, int lda, int ldb, int ldc, int Khalf)
{
    __shared__ __align__(16) __half smem[16384];
    const int z = blockIdx.z;
    gemm_body<0, float>(smem, A + z * Khalf, B + z * Khalf,
                        C + (long)z * LQ * CDIM,
                        lda, ldb, ldc, Khalf, blockIdx.x, blockIdx.x, blockIdx.y,
                        nullptr, 0, 1.0f, nullptr);
}

// ---------------------------------------------------------------------------
// Fused attention tile kernel (max-free softmax, log2-domain scores).
// v9: v1/v5 inner structure byte-identical; ONLY change is the XCD-affinity
// block remap (proven in v2 to cut FETCH 135->22MB): the 16 q-blocks sharing
// one (h,kc) K/V chunk (1MB) land on one XCD -> 4 chunks = 4MB = one L2.
// Theory: K/V from local L2 (~200cy) vs HBM (~900cy) shortens the per-step
// vmcnt(0)+barrier drain.
// ---------------------------------------------------------------------------
__global__ __launch_bounds__(256, 2) void attn_tile(
    const __half* __restrict__ Qf,  // [2048][2048] normed+roped, log2-scaled
    const __half* __restrict__ Kf,  // kvf [4096][4096]; K in cols 0..2047
    const __half* __restrict__ Vt,  // [2048][4096]  Vt[h*128+d][key]
    float* __restrict__ Opart,      // [2][2048][2048]
    float* __restrict__ lsum)       // [16][2048]
{
    __shared__ __align__(16) __half lK[64 * 128];   // 16 KB
    __shared__ __align__(16) __half lV[128 * 64];   // 16 KB
    __shared__ __align__(16) __half pL[4 * 2 * 16 * 76];  // 19 KB

    const int tid  = threadIdx.x;
    const int lane = tid & 63;
    const int wave = tid >> 6;
    const int l15  = lane & 15;
    const int quad = lane >> 4;
    // XCD-affinity remap (bijective on 512 blocks): same-hkc blocks have
    // lin = const (mod 32) -> const (mod 8) -> same XCD (round-robin).
    const int lin = blockIdx.y * 16 + blockIdx.x;
    const int hkc = (lin & 7) * 4 + ((lin >> 3) & 3);
    const int qt  = lin >> 5;                 // 0..15
    const int h   = hkc >> 1;
    const int kc  = hkc & 1;
    const int q0  = qt * 128 + wave * 32;     // this wave's 32 q-rows

    // Q A-fragments: A[m=l15][k=ks*32+quad*8+j]
    f16x8 aq[2][4];
#pragma unroll
    for (int mt = 0; mt < 2; ++mt)
#pragma unroll
        for (int ks = 0; ks < 4; ++ks)
            aq[mt][ks] = *(const f16x8*)&Qf[(long)(q0 + mt * 16 + l15) * CDIM +
                                            h * HDIM + ks * 32 + quad * 8];

    // staging pointers. LDS[r][g] = global[r][g ^ (r & mask)] (XOR swizzle in
    // the SOURCE address; LDS dest is wave-uniform base + lane*16).
    const int rK = tid >> 4;          // K row 0..15 (+16/issue)
    const int gK = tid & 15;          // 16 groups of 8 halves
    const __half* srcK = Kf + (long)(kc * 2048 + rK) * 4096 + h * HDIM +
                         ((gK ^ (rK & 15)) << 3);
    const int rV = tid >> 3;          // V row (d) 0..31 (+32/issue)
    const int gV = tid & 7;           // 8 groups of 8 halves
    const __half* srcV = Vt + (long)(h * HDIM + rV) * (long)LKEY + kc * 2048 +
                         ((gV ^ (rV & 7)) << 3);
    __half* dstK = lK + tid * 8;
    __half* dstV = lV + tid * 8;

    f32x4 accO[2][8] = {};
    f32x4 l_acc[2] = {};

    for (int st = 0; st < 32; ++st) {
#pragma unroll
        for (int i = 0; i < 4; ++i) {
            GLOAD_LDS16(srcK + (long)(st * 64 + i * 16) * 4096, dstK + i * 2048);
            GLOAD_LDS16(srcV + (long)i * 32 * LKEY + st * 64, dstV + i * 2048);
        }
        __syncthreads();
        // ---- QK^T (acc init -10 folds the exp2 bias) ----
        f32x4 s[2][4];
#pragma unroll
        for (int mt = 0; mt < 2; ++mt)
#pragma unroll
            for (int nt = 0; nt < 4; ++nt)
                s[mt][nt] = (f32x4){-10.f, -10.f, -10.f, -10.f};
#pragma unroll
        for (int nt = 0; nt < 4; ++nt) {
            const int n = nt * 16 + l15;
#pragma unroll
            for (int ks = 0; ks < 4; ++ks) {
                const f16x8 kf = *(const f16x8*)
                    &lK[n * 128 + (((ks * 4 + quad) ^ (n & 15)) << 3)];
                s[0][nt] = MFMA16(aq[0][ks], kf, s[0][nt]);
                s[1][nt] = MFMA16(aq[1][ks], kf, s[1][nt]);
            }
        }
        // ---- P = exp2(s), accumulate l, stage P (per-wave slab) ----
#pragma unroll
        for (int mt = 0; mt < 2; ++mt)
#pragma unroll
            for (int nt = 0; nt < 4; ++nt)
#pragma unroll
                for (int r2 = 0; r2 < 4; ++r2) {
                    const float p = __builtin_amdgcn_exp2f(s[mt][nt][r2]);
                    l_acc[mt][r2] += p;
                    pL[((wave * 2 + mt) * 16 + quad * 4 + r2) * 76 +
                       nt * 16 + l15] = __float2half(p);
                }
        // ---- PV ----
        f16x8 ap[2][2];
#pragma unroll
        for (int mt = 0; mt < 2; ++mt) {
            ap[mt][0] = *(const f16x8*)&pL[((wave * 2 + mt) * 16 + l15) * 76 + quad * 8];
            ap[mt][1] = *(const f16x8*)&pL[((wave * 2 + mt) * 16 + l15) * 76 + 32 + quad * 8];
        }
#pragma unroll
        for (int nt2 = 0; nt2 < 8; ++nt2) {
            const int n2 = nt2 * 16 + l15;
            const f16x8 v0 = *(const f16x8*)&lV[n2 * 64 + ((quad ^ (n2 & 7)) << 3)];
            const f16x8 v1 = *(const f16x8*)&lV[n2 * 64 + (((4 + quad) ^ (n2 & 7)) << 3)];
            accO[0][nt2] = MFMA16(ap[0][0], v0, accO[0][nt2]);
            accO[0][nt2] = MFMA16(ap[0][1], v1, accO[0][nt2]);
            accO[1][nt2] = MFMA16(ap[1][0], v0, accO[1][nt2]);
            accO[1][nt2] = MFMA16(ap[1][1], v1, accO[1][nt2]);
        }
        __syncthreads();
    }

    // ---- l: reduce across the 16 l15 lanes, publish via atomics ----
#pragma unroll
    for (int mt = 0; mt < 2; ++mt)
#pragma unroll
        for (int r2 = 0; r2 < 4; ++r2) {
            float v = l_acc[mt][r2];
            v += __shfl_xor(v, 1);
            v += __shfl_xor(v, 2);
            v += __shfl_xor(v, 4);
            v += __shfl_xor(v, 8);
            if (l15 == 0)
                atomicAdd(&lsum[h * LQ + q0 + mt * 16 + quad * 4 + r2], v);
        }
    // ---- O partial (fp32) ----
    float* Cp = Opart + (long)kc * LQ * CDIM + h * HDIM;
#pragma unroll
    for (int mt = 0; mt < 2; ++mt)
#pragma unroll
        for (int nt2 = 0; nt2 < 8; ++nt2)
#pragma unroll
            for (int rx = 0; rx < 4; ++rx)
                Cp[(long)(q0 + mt * 16 + quad * 4 + rx) * CDIM + nt2 * 16 + l15] =
                    accO[mt][nt2][rx];
}

// ---------------------------------------------------------------------------
// merge: a2[q][c] = (Op0+Op1)[q][c] / lsum[c>>7][q]   (fp16 out)
// ---------------------------------------------------------------------------
__global__ __launch_bounds__(256) void merge_o(
    const float* __restrict__ Op, const float* __restrict__ lsum,
    __half* __restrict__ a2)
{
    const int row = blockIdx.x;
    const int c0  = threadIdx.x * 8;
    const float inv = 1.0f / lsum[(c0 >> 7) * LQ + row];
    const float* p0 = Op + (long)row * CDIM + c0;
    const float* p1 = p0 + (long)LQ * CDIM;
    union { f16x8 v; _Float16 e[8]; } o;
#pragma unroll
    for (int j = 0; j < 8; ++j)
        o.e[j] = (_Float16)((p0[j] + p1[j]) * inv);
    *(f16x8*)&a2[(long)row * 4096 + c0] = o.v;
}

// ---------------------------------------------------------------------------
// ONE prep launch: 6 casts + Wo pack + sw2^T + sin features + lsum zero.
// ---------------------------------------------------------------------------
__global__ __launch_bounds__(256) void prep_all(
    const float* __restrict__ h2, const float* __restrict__ h0,
    const float* __restrict__ h1, const float* __restrict__ Wq,
    const float* __restrict__ Wk, const float* __restrict__ Wv,
    const float* __restrict__ Wo, const float* __restrict__ sw1,
    const float* __restrict__ sb1, const float* __restrict__ sw2,
    __half* __restrict__ xq, __half* __restrict__ xkv,
    __half* __restrict__ wqh, __half* __restrict__ wkv,
    __half* __restrict__ a2, __half* __restrict__ b2,
    float* __restrict__ lsum)
{
    __shared__ float t[64][65];
    const int blk = blockIdx.x;
    const int tid = threadIdx.x;
    if (blk < 24576) {
        // six fp32->fp16 casts, 4 elem/thread
        const long i = ((long)blk * 256 + tid) << 2;
        const int chunk = (int)(i >> 22);
        const long off = i & 4194303;
        const float* s; __half* d;
        switch (chunk) {
            case 0:  s = h2; d = xq;            break;
            case 1:  s = h0; d = xkv;           break;
            case 2:  s = h1; d = xkv + 4194304; break;
            case 3:  s = Wq; d = wqh;           break;
            case 4:  s = Wk; d = wkv;           break;
            default: s = Wv; d = wkv + 4194304; break;
        }
        const float4 v = *(const float4*)&s[off];
        f16x4 o;
        o[0] = (_Float16)v.x; o[1] = (_Float16)v.y;
        o[2] = (_Float16)v.z; o[3] = (_Float16)v.w;
        *(f16x4*)&d[off] = o;
    } else if (blk < 28672) {
        // Wo -> b2 left half (row o of b2 is 4096 wide)
        const int i = ((blk - 24576) * 256 + tid) << 2;
        const int o = i >> 11, c = i & 2047;
        const float4 v = *(const float4*)&Wo[i];
        f16x4 w4;
        w4[0] = (_Float16)v.x; w4[1] = (_Float16)v.y;
        w4[2] = (_Float16)v.z; w4[3] = (_Float16)v.w;
        *(f16x4*)&b2[((long)o << 12) + c] = w4;
    } else if (blk < 29696) {
        // sw2^T -> b2 right half (64x64 LDS transpose tiles)
        const int lb = blk - 28672;          // 0..1023
        const long r0 = (long)(lb & 31) * 64;
        const long c0 = (long)(lb >> 5) * 64;
        const int tj = tid & 63;
        const int ti = tid >> 6;
#pragma unroll
        for (int it = 0; it < 16; ++it) {
            const int i = it * 4 + ti;
            t[i][tj] = sw2[(r0 + i) * 2048 + c0 + tj];
        }
        __syncthreads();
#pragma unroll
        for (int it = 0; it < 16; ++it) {
            const int i = it * 4 + ti;
            b2[(c0 + i) * 4096 + 2048 + r0 + tj] = __float2half(t[tj][i]);
        }
    } else if (blk < 33792) {
        // sin positional features -> a2 right half
        const int i = ((blk - 29696) * 256 + tid) << 2;
        const int l = i >> 11, c = i & 2047;
        const float coord = -1.0f + (2.0f / 2047.0f) * (float)l;
        const float4 w = *(const float4*)&sw1[c];
        const float4 b = *(const float4*)&sb1[c];
        f16x4 o;
        o[0] = (_Float16)__sinf(30.0f * (coord * w.x + b.x));
        o[1] = (_Float16)__sinf(30.0f * (coord * w.y + b.y));
        o[2] = (_Float16)__sinf(30.0f * (coord * w.z + b.z));
        o[3] = (_Float16)__sinf(30.0f * (coord * w.w + b.w));
        *(f16x4*)&a2[((long)l << 12) + 2048 + c] = o;
    } else {
        // zero lsum (16*2048 floats)
        const int i = ((blk - 33792) * 256 + tid) << 2;
        *(float4*)&lsum[i] = (float4){0.f, 0.f, 0.f, 0.f};
    }
}

__global__ __launch_bounds__(256) void final_norm(
    const float* __restrict__ out2, const float* __restrict__ x,
    const float* __restrict__ sb2, const float* __restrict__ on_w,
    float* __restrict__ y)
{
    const int row = blockIdx.x;
    const float* o0 = out2 + (long)row * CDIM;
    const float* o1 = o0 + (long)LQ * CDIM;   // split-K partial #2
    float4 v[2];
    float ss = 0.f;
#pragma unroll
    for (int i = 0; i < 2; ++i) {
        const int c = threadIdx.x * 4 + i * 1024;
        const float4 a = *(const float4*)&o0[c];
        const float4 b = *(const float4*)&o1[c];
        const float4 s = *(const float4*)&sb2[c];
        float4 tv;
        tv.x = a.x + b.x + s.x; tv.y = a.y + b.y + s.y;
        tv.z = a.z + b.z + s.z; tv.w = a.w + b.w + s.w;
        v[i] = tv;
        ss += tv.x * tv.x + tv.y * tv.y + tv.z * tv.z + tv.w * tv.w;
    }
#pragma unroll
    for (int off = 1; off < 64; off <<= 1) ss += __shfl_xor(ss, off);
    __shared__ float red[4];
    const int lane = threadIdx.x & 63, wv = threadIdx.x >> 6;
    if (lane == 0) red[wv] = ss;
    __syncthreads();
    const float tot = red[0] + red[1] + red[2] + red[3];
    const float rn = rsqrtf(tot * (1.0f / 2048.0f) + 1e-6f);
#pragma unroll
    for (int i = 0; i < 2; ++i) {
        const int c = threadIdx.x * 4 + i * 1024;
        const float4 xr = *(const float4*)&x[(long)row * CDIM + c];
        const float4 wv4 = *(const float4*)&on_w[c];
        float4 o;
        o.x = xr.x + v[i].x * rn * wv4.x;
        o.y = xr.y + v[i].y * rn * wv4.y;
        o.z = xr.z + v[i].z * rn * wv4.z;
        o.w = xr.w + v[i].w * rn * wv4.w;
        *(float4*)&y[(long)row * CDIM + c] = o;
    }
}

// ---------------------------------------------------------------------------
extern "C" void kernel_launch(void* const* d_in, const int* in_sizes, int n_in,
                              void* d_out, int out_size, void* d_ws, size_t ws_size,
                              hipStream_t stream) {
    const float* x    = (const float*)d_in[0];
    const float* h0   = (const float*)d_in[1];
    const float* h1   = (const float*)d_in[2];
    const float* h2   = (const float*)d_in[3];
    const float* Wq   = (const float*)d_in[4];
    const float* Wk   = (const float*)d_in[5];
    const float* Wv   = (const float*)d_in[6];
    const float* Wo   = (const float*)d_in[7];
    const float* qn_w = (const float*)d_in[8];
    const float* kn_w = (const float*)d_in[9];
    const float* on_w = (const float*)d_in[10];
    const float* sw1  = (const float*)d_in[11];
    const float* sb1  = (const float*)d_in[12];
    const float* sw2  = (const float*)d_in[13];
    const float* sb2  = (const float*)d_in[14];
    float* y = (float*)d_out;

    const size_t MB = 1ull << 20;
    char* w = (char*)d_ws;
    __half* xq  = (__half*)(w);             //  8 MB  h2 fp16   [xq;xkv] contiguous
    __half* xkv = (__half*)(w + 8 * MB);    // 16 MB  [h0;h1] fp16
    __half* wqh = (__half*)(w + 24 * MB);   //  8 MB  Wq fp16
    __half* wkv = (__half*)(w + 32 * MB);   // 16 MB  [Wk;Wv] fp16
    __half* qf  = (__half*)(w + 48 * MB);   //  8 MB  Q proj, normed+roped
    __half* kvf = (__half*)(w + 56 * MB);   // 32 MB  K normed (cols 0..2047)
    __half* vT  = (__half*)(w + 88 * MB);   // 16 MB  V transposed (2048x4096)
    __half* a2  = (__half*)(w + 104 * MB);  // 16 MB  [attn_out | sin_feat]
    __half* b2  = (__half*)(w + 120 * MB);  // 16 MB  [Wo | sw2^T]
    float* lsum  = (float*)(w + 136 * MB);  // 128 KB (fresh, zeroed in prep)
    float* Opart = (float*)(w);             // 32 MB  overlays xq/xkv (dead)
    float* out2  = (float*)(w);             // 32 MB  [2] split-K partials,
                                            //        overlays Opart (dead after merge_o)
    (void)in_sizes; (void)n_in; (void)out_size; (void)ws_size;

    // one prep launch: 6 casts + Wo pack + sw2^T + sin features + lsum zero
    prep_all<<<33824, 256, 0, stream>>>(h2, h0, h1, Wq, Wk, Wv, Wo, sw1, sb1,
                                        sw2, xq, xkv, wqh, wkv, a2, b2, lsum);

    // fused: projections + rmsnorm + rope (Q scaled by log2(e)/sqrt(D)) + V^T
    gemm_qkv<<<1280, 256, 0, stream>>>(xq, wqh, wkv, qf, kvf, vT, qn_w, kn_w);

    attn_tile<<<dim3(16, 32), 256, 0, stream>>>(qf, kvf, vT, Opart, lsum);
    merge_o<<<2048, 256, 0, stream>>>(Opart, lsum, a2);

    gemm_sk<<<dim3(16, 16, 2), 256, 0, stream>>>(a2, b2, out2, 4096, 4096, 2048, 2048);
    final_norm<<<2048, 256, 0, stream>>>(out2, x, sb2, on_w, y);
}

// Round 9
// 435.647 us; speedup vs baseline: 1.0717x; 1.0235x over previous
//
#include <hip/hip_runtime.h>
#include <hip/hip_fp16.h>

// Problem constants: B=1, L=2048, C=2048, H=16, D=128, keys = 2L = 4096
#define LQ 2048
#define CDIM 2048
#define NHEAD 16
#define HDIM 128
#define LKEY 4096

typedef _Float16 f16x8 __attribute__((ext_vector_type(8)));
typedef _Float16 f16x4 __attribute__((ext_vector_type(4)));
typedef float f32x4 __attribute__((ext_vector_type(4)));

#define GLOAD_LDS16(g, s) __builtin_amdgcn_global_load_lds( \
    (const __attribute__((address_space(1))) void*)(g),     \
    (__attribute__((address_space(3))) void*)(s), 16, 0, 0)

#define MFMA16(a, b, c) __builtin_amdgcn_mfma_f32_16x16x32_f16(a, b, c, 0, 0, 0)

__device__ __forceinline__ void storeC(float* p, float v) { *p = v; }
__device__ __forceinline__ void storeC(__half* p, float v) { *p = __float2half(v); }

// ---------------------------------------------------------------------------
// Shared 128x128 GEMM body (m97 structure) — used by gemm_q and gemm_sk.
// MODE 0: plain store. MODE 1: fused rmsnorm+rope epilogue (fp16).
// ---------------------------------------------------------------------------
template <int MODE, typename OutT>
__device__ __forceinline__ void gemm_body(
    __half* smem,
    const __half* __restrict__ A, const __half* __restrict__ B,
    OutT* __restrict__ C, int lda, int ldb, int ldc, int K,
    int bmA, int bmC, int bn,
    const float* __restrict__ wgt, int kmode, float oscale)
{
    __half* lA = smem;
    __half* lB = smem + 8192;
    const int tid  = threadIdx.x;
    const int lane = tid & 63;
    const int wave = tid >> 6;
    const int r = tid >> 3;
    const int g = tid & 7;
    const __half* gA = A + (long)(bmA * 128 + r) * lda + ((g ^ (r & 7)) << 3);
    const __half* gB = B + (long)(bn * 128 + r) * ldb + ((g ^ (r & 7)) << 3);
    __half* lAp = lA + tid * 8;
    __half* lBp = lB + tid * 8;
    const int wr = (wave & 1) << 6;
    const int wc = (wave >> 1) << 6;
    const int l15 = lane & 15, quad = lane >> 4;

    f32x4 acc[4][4] = {};

    for (int kt = 0; kt < K; kt += 64) {
#pragma unroll
        for (int i = 0; i < 4; ++i) {
            GLOAD_LDS16(gA + (long)i * 32 * lda, lAp + i * 2048);
            GLOAD_LDS16(gB + (long)i * 32 * ldb, lBp + i * 2048);
        }
        gA += 64; gB += 64;
        __syncthreads();
#pragma unroll
        for (int kk = 0; kk < 2; ++kk) {
            f16x8 af[4], bfr[4];
#pragma unroll
            for (int mi = 0; mi < 4; ++mi) {
                const int m = wr + mi * 16 + l15;
                const int kg = kk * 4 + quad;
                af[mi] = *(const f16x8*)&lA[m * 64 + ((kg ^ (m & 7)) << 3)];
            }
#pragma unroll
            for (int ni = 0; ni < 4; ++ni) {
                const int n = wc + ni * 16 + l15;
                const int kg = kk * 4 + quad;
                bfr[ni] = *(const f16x8*)&lB[n * 64 + ((kg ^ (n & 7)) << 3)];
            }
#pragma unroll
            for (int mi = 0; mi < 4; ++mi)
#pragma unroll
                for (int ni = 0; ni < 4; ++ni)
                    acc[mi][ni] = MFMA16(af[mi], bfr[ni], acc[mi][ni]);
        }
        __syncthreads();
    }

    if constexpr (MODE == 0) {
        const int row0 = bmC * 128 + wr + quad * 4;
        const int col0 = bn * 128 + wc + l15;
#pragma unroll
        for (int mi = 0; mi < 4; ++mi)
#pragma unroll
            for (int ni = 0; ni < 4; ++ni)
#pragma unroll
                for (int rx = 0; rx < 4; ++rx)
                    storeC(&C[(long)(row0 + mi * 16 + rx) * ldc + col0 + ni * 16],
                           acc[mi][ni][rx]);
    } else {
        // MODE 1: rmsnorm + rope fused. Tile cols = one head's D=128.
        __half* sT = smem;   // [128][136] fp16, aliases lA/lB (dead)
#pragma unroll
        for (int mi = 0; mi < 4; ++mi)
#pragma unroll
            for (int ni = 0; ni < 4; ++ni)
#pragma unroll
                for (int rx = 0; rx < 4; ++rx)
                    sT[(wr + mi * 16 + quad * 4 + rx) * 136 + wc + ni * 16 + l15] =
                        (_Float16)acc[mi][ni][rx];
        __syncthreads();
        const int row = (wave << 5) + (lane >> 1);
        const int c0  = (lane & 1) << 5;
        const __half* rp = sT + row * 136;
        f16x8 L[4], Hh[4];
#pragma unroll
        for (int j8 = 0; j8 < 4; ++j8) {
            L[j8]  = *(const f16x8*)&rp[c0 + j8 * 8];
            Hh[j8] = *(const f16x8*)&rp[c0 + 64 + j8 * 8];
        }
        float ss = 0.f;
#pragma unroll
        for (int j8 = 0; j8 < 4; ++j8)
#pragma unroll
            for (int e = 0; e < 8; ++e) {
                const float a = (float)L[j8][e], b = (float)Hh[j8][e];
                ss += a * a + b * b;
            }
        ss += __shfl_xor(ss, 1);
        const float rn = rsqrtf(ss * (1.0f / 128.0f) + 1e-6f);
        const long grow = (long)bmC * 128 + row;
        const int depth = kmode ? (grow < 2048 ? 0 : 1) : 2;
        union { f16x8 v; _Float16 e[8]; } o1[4], o2[4];
#pragma unroll
        for (int j8 = 0; j8 < 4; ++j8)
#pragma unroll
            for (int e = 0; e < 8; ++e) {
                const int d = c0 + j8 * 8 + e;
                const float x1 = (float)L[j8][e]  * rn * wgt[d];
                const float x2 = (float)Hh[j8][e] * rn * wgt[d + 64];
                const float ang = (float)depth *
                    exp2f(-(float)d * 0.20762050593045702f);
                float sn, cs;
                __sincosf(ang, &sn, &cs);
                o1[j8].e[e] = (_Float16)((x1 * cs - x2 * sn) * oscale);
                o2[j8].e[e] = (_Float16)((x1 * sn + x2 * cs) * oscale);
            }
        __half* op = (__half*)C + grow * ldc + bn * 128;
#pragma unroll
        for (int j8 = 0; j8 < 4; ++j8) {
            *(f16x8*)&op[c0 + j8 * 8]      = o1[j8].v;
            *(f16x8*)&op[c0 + 64 + j8 * 8] = o2[j8].v;
        }
    }
}

// ---------------------------------------------------------------------------
// 8-phase 256x256 KV projection GEMM (catalog T2+T3+T4+T5 port).
// C = xkv(4096x2048) * wkv(4096x2048)^T. 256 blocks = 1/CU, 512 thr = 8 waves
// (wm=wave>>2, wn=wave&3; per-wave C: 128x64). LDS = 8 half-tile slots x16KB
// (A/B x dbuf x half). Per K-tile: 4 phases, each {stage 1 half-tile of tile
// t+1 into buf^1, [vmcnt(2) at q0 only], s_barrier, ds-read quadrant (XOR-
// swizzled), setprio(1), 16 MFMA, setprio(0), s_barrier}. vmcnt never 0 in
// loop: at tile t's q0, outstanding = t's 8 loads + 2 just-issued -> vmcnt(2)
// retires exactly tile t's staging. WAR safe: buf^1 slots last read at tile
// t-1, closed by its post-MFMA barrier. Epilogue: bn<8 -> in-LDS rmsnorm+rope
// into kvf; bn>=8 -> transposed V store into vT.
// ---------------------------------------------------------------------------
__device__ __forceinline__ void stage_half(
    const __half* __restrict__ M, long row0, int T, char* lds, int slot, int tid)
{
    char* dst = lds + slot * 16384 + tid * 16;
    const int r = tid >> 3;            // 0..63
    const int g = tid & 7;
    const int co = T * 64 + ((g ^ (r & 7)) << 3);
    GLOAD_LDS16(M + (row0 + r) * 2048 + co, dst);
    GLOAD_LDS16(M + (row0 + r + 64) * 2048 + co, dst + 8192);  // (r+64)&7 == r&7
}

__global__ __launch_bounds__(512, 1) void gemm_kv8(
    const __half* __restrict__ A,   // xkv 4096x2048
    const __half* __restrict__ B,   // wkv 4096x2048
    __half* __restrict__ Ckv,       // kvf 4096x4096 (K half: cols 0..2047)
    __half* __restrict__ vT,        // 2048x4096
    const float* __restrict__ kn_w)
{
    __shared__ __align__(16) char LDS[131072];
    const int tid  = threadIdx.x;
    const int lane = tid & 63;
    const int wave = tid >> 6;
    const int wm = wave >> 2;           // 0..1
    const int wn = wave & 3;            // 0..3
    const int l15 = lane & 15, quad = lane >> 4;
    const int bm = blockIdx.x & 15;
    const int bn = blockIdx.x >> 4;
    const long arow = (long)bm * 256;
    const long brow = (long)bn * 256;

    f32x4 acc[8][4] = {};

    // prologue: tile 0 into buf0 (slots: A = 0+buf*2+half, B = 4+buf*2+half)
    stage_half(A, arow,       0, LDS, 0, tid);
    stage_half(A, arow + 128, 0, LDS, 1, tid);
    stage_half(B, brow,       0, LDS, 4, tid);
    stage_half(B, brow + 128, 0, LDS, 5, tid);

    for (int tt = 0; tt < 32; ++tt) {
        const int buf = tt & 1, sbuf = buf ^ 1;
        const int Tn = (tt < 31) ? tt + 1 : 31;   // last iter: dummy re-stage
        const __half* As = (const __half*)(LDS + (buf * 2 + wm) * 16384);
        const __half* Bs = (const __half*)(LDS + (4 + buf * 2 + (wn >> 1)) * 16384);
        f16x8 bq[4][2];
#pragma unroll
        for (int q = 0; q < 4; ++q) {
            // ---- stage one half-tile of tile Tn into buf^1 ----
            if (q == 0)      stage_half(A, arow,       Tn, LDS, 0 + sbuf * 2, tid);
            else if (q == 1) stage_half(A, arow + 128, Tn, LDS, 1 + sbuf * 2, tid);
            else if (q == 2) stage_half(B, brow,       Tn, LDS, 4 + sbuf * 2, tid);
            else             stage_half(B, brow + 128, Tn, LDS, 5 + sbuf * 2, tid);
            if (q == 0)
                asm volatile("s_waitcnt vmcnt(2)" ::: "memory");
            __builtin_amdgcn_s_barrier();
            __builtin_amdgcn_sched_barrier(0);
            // ---- ds reads (XOR-swizzled, conflict-free) ----
            if (q == 0) {
#pragma unroll
                for (int ni = 0; ni < 4; ++ni) {
                    const int rb = ((wn & 1) << 6) + ni * 16 + l15;
#pragma unroll
                    for (int ks = 0; ks < 2; ++ks)
                        bq[ni][ks] = *(const f16x8*)
                            &Bs[rb * 64 + (((ks * 4 + quad) ^ (rb & 7)) << 3)];
                }
            }
            f16x8 av[2][2];
#pragma unroll
            for (int m2 = 0; m2 < 2; ++m2) {
                const int ra = (q * 2 + m2) * 16 + l15;
#pragma unroll
                for (int ks = 0; ks < 2; ++ks)
                    av[m2][ks] = *(const f16x8*)
                        &As[ra * 64 + (((ks * 4 + quad) ^ (ra & 7)) << 3)];
            }
            __builtin_amdgcn_s_setprio(1);
#pragma unroll
            for (int m2 = 0; m2 < 2; ++m2)
#pragma unroll
                for (int ni = 0; ni < 4; ++ni) {
                    acc[q * 2 + m2][ni] = MFMA16(av[m2][0], bq[ni][0], acc[q * 2 + m2][ni]);
                    acc[q * 2 + m2][ni] = MFMA16(av[m2][1], bq[ni][1], acc[q * 2 + m2][ni]);
                }
            __builtin_amdgcn_s_setprio(0);
            __builtin_amdgcn_s_barrier();
            __builtin_amdgcn_sched_barrier(0);
        }
    }

    __syncthreads();   // full drain (incl. dummy stages) before LDS reuse

    if (bn < 8) {
        // K half: restage C tile in LDS, rmsnorm+rope per (row, head)
        __half* sT = (__half*)LDS;   // [256][256] (one-time pass; conflicts ok)
#pragma unroll
        for (int mi = 0; mi < 8; ++mi)
#pragma unroll
            for (int ni = 0; ni < 4; ++ni)
#pragma unroll
                for (int rx = 0; rx < 4; ++rx)
                    sT[(wm * 128 + mi * 16 + quad * 4 + rx) * 256 +
                       wn * 64 + ni * 16 + l15] = (_Float16)acc[mi][ni][rx];
        __syncthreads();
        const int row = tid >> 1;
        const int hs  = tid & 1;
        const __half* rp = sT + row * 256 + hs * 128;
        f16x8 xv[16];
#pragma unroll
        for (int j = 0; j < 16; ++j) xv[j] = *(const f16x8*)&rp[j * 8];
        float ss = 0.f;
#pragma unroll
        for (int j = 0; j < 16; ++j)
#pragma unroll
            for (int e = 0; e < 8; ++e) {
                const float v = (float)xv[j][e];
                ss += v * v;
            }
        const float rn = rsqrtf(ss * (1.0f / 128.0f) + 1e-6f);
        const long R = arow + row;
        const float depth = (R < 2048) ? 0.f : 1.f;
        __half* op = Ckv + R * 4096 + bn * 256 + hs * 128;
#pragma unroll
        for (int j = 0; j < 8; ++j) {
            union { f16x8 v; _Float16 e[8]; } o1, o2;
#pragma unroll
            for (int e = 0; e < 8; ++e) {
                const int d = j * 8 + e;
                const float x1 = (float)xv[j][e]     * rn * kn_w[d];
                const float x2 = (float)xv[j + 8][e] * rn * kn_w[d + 64];
                const float ang = depth * exp2f(-(float)d * 0.20762050593045702f);
                float sn, cs;
                __sincosf(ang, &sn, &cs);
                o1.e[e] = (_Float16)(x1 * cs - x2 * sn);
                o2.e[e] = (_Float16)(x1 * sn + x2 * cs);
            }
            *(f16x8*)&op[j * 8]      = o1.v;
            *(f16x8*)&op[64 + j * 8] = o2.v;
        }
    } else {
        // V half: transposed store vT[d][key]
#pragma unroll
        for (int mi = 0; mi < 8; ++mi)
#pragma unroll
            for (int ni = 0; ni < 4; ++ni)
#pragma unroll
                for (int rx = 0; rx < 4; ++rx) {
                    const int d = (bn - 8) * 256 + wn * 64 + ni * 16 + l15;
                    const long key = arow + wm * 128 + mi * 16 + quad * 4 + rx;
                    vT[(long)d * LKEY + key] = __float2half(acc[mi][ni][rx]);
                }
    }
}

// ---------------------------------------------------------------------------
// Q projection GEMM (old proven 128² path, fused rmsnorm+rope, 256 blocks).
// ---------------------------------------------------------------------------
__global__ __launch_bounds__(256, 2) void gemm_q(
    const __half* __restrict__ A, const __half* __restrict__ Bq,
    __half* __restrict__ Cq, const float* __restrict__ qn_w)
{
    __shared__ __align__(16) __half smem[17408];
    const int bm = blockIdx.x & 15, bn = blockIdx.x >> 4;
    gemm_body<1, __half>(smem, A, Bq, Cq, 2048, 2048, 2048, 2048,
                         bm, bm, bn, qn_w, 0, 0.12751743f);
}

// ---------------------------------------------------------------------------
// Split-K x2 final GEMM: grid (16,16,2) = 512 blocks, (256,2) proven config.
// ---------------------------------------------------------------------------
__global__ __launch_bounds__(256, 2) void gemm_sk(
    const __half* __restrict__ A, const __half* __restrict__ B,
    float* __restrict__ C, int lda, int ldb, int ldc, int Khalf)
{
    __shared__ __align__(16) __half smem[16384];
    const int z = blockIdx.z;
    gemm_body<0, float>(smem, A + z * Khalf, B + z * Khalf,
                        C + (long)z * LQ * CDIM,
                        lda, ldb, ldc, Khalf, blockIdx.x, blockIdx.x, blockIdx.y,
                        nullptr, 0, 1.0f);
}

// ---------------------------------------------------------------------------
// Fused attention tile kernel (max-free softmax, log2-domain scores).
// v9 structure: v1 inner loop + XCD-affinity remap. Unchanged.
// ---------------------------------------------------------------------------
__global__ __launch_bounds__(256, 2) void attn_tile(
    const __half* __restrict__ Qf,
    const __half* __restrict__ Kf,
    const __half* __restrict__ Vt,
    float* __restrict__ Opart,
    float* __restrict__ lsum)
{
    __shared__ __align__(16) __half lK[64 * 128];
    __shared__ __align__(16) __half lV[128 * 64];
    __shared__ __align__(16) __half pL[4 * 2 * 16 * 76];

    const int tid  = threadIdx.x;
    const int lane = tid & 63;
    const int wave = tid >> 6;
    const int l15  = lane & 15;
    const int quad = lane >> 4;
    const int lin = blockIdx.y * 16 + blockIdx.x;
    const int hkc = (lin & 7) * 4 + ((lin >> 3) & 3);
    const int qt  = lin >> 5;
    const int h   = hkc >> 1;
    const int kc  = hkc & 1;
    const int q0  = qt * 128 + wave * 32;

    f16x8 aq[2][4];
#pragma unroll
    for (int mt = 0; mt < 2; ++mt)
#pragma unroll
        for (int ks = 0; ks < 4; ++ks)
            aq[mt][ks] = *(const f16x8*)&Qf[(long)(q0 + mt * 16 + l15) * CDIM +
                                            h * HDIM + ks * 32 + quad * 8];

    const int rK = tid >> 4;
    const int gK = tid & 15;
    const __half* srcK = Kf + (long)(kc * 2048 + rK) * 4096 + h * HDIM +
                         ((gK ^ (rK & 15)) << 3);
    const int rV = tid >> 3;
    const int gV = tid & 7;
    const __half* srcV = Vt + (long)(h * HDIM + rV) * (long)LKEY + kc * 2048 +
                         ((gV ^ (rV & 7)) << 3);
    __half* dstK = lK + tid * 8;
    __half* dstV = lV + tid * 8;

    f32x4 accO[2][8] = {};
    f32x4 l_acc[2] = {};

    for (int st = 0; st < 32; ++st) {
#pragma unroll
        for (int i = 0; i < 4; ++i) {
            GLOAD_LDS16(srcK + (long)(st * 64 + i * 16) * 4096, dstK + i * 2048);
            GLOAD_LDS16(srcV + (long)i * 32 * LKEY + st * 64, dstV + i * 2048);
        }
        __syncthreads();
        f32x4 s[2][4];
#pragma unroll
        for (int mt = 0; mt < 2; ++mt)
#pragma unroll
            for (int nt = 0; nt < 4; ++nt)
                s[mt][nt] = (f32x4){-10.f, -10.f, -10.f, -10.f};
#pragma unroll
        for (int nt = 0; nt < 4; ++nt) {
            const int n = nt * 16 + l15;
#pragma unroll
            for (int ks = 0; ks < 4; ++ks) {
                const f16x8 kf = *(const f16x8*)
                    &lK[n * 128 + (((ks * 4 + quad) ^ (n & 15)) << 3)];
                s[0][nt] = MFMA16(aq[0][ks], kf, s[0][nt]);
                s[1][nt] = MFMA16(aq[1][ks], kf, s[1][nt]);
            }
        }
#pragma unroll
        for (int mt = 0; mt < 2; ++mt)
#pragma unroll
            for (int nt = 0; nt < 4; ++nt)
#pragma unroll
                for (int r2 = 0; r2 < 4; ++r2) {
                    const float p = __builtin_amdgcn_exp2f(s[mt][nt][r2]);
                    l_acc[mt][r2] += p;
                    pL[((wave * 2 + mt) * 16 + quad * 4 + r2) * 76 +
                       nt * 16 + l15] = __float2half(p);
                }
        f16x8 ap[2][2];
#pragma unroll
        for (int mt = 0; mt < 2; ++mt) {
            ap[mt][0] = *(const f16x8*)&pL[((wave * 2 + mt) * 16 + l15) * 76 + quad * 8];
            ap[mt][1] = *(const f16x8*)&pL[((wave * 2 + mt) * 16 + l15) * 76 + 32 + quad * 8];
        }
#pragma unroll
        for (int nt2 = 0; nt2 < 8; ++nt2) {
            const int n2 = nt2 * 16 + l15;
            const f16x8 v0 = *(const f16x8*)&lV[n2 * 64 + ((quad ^ (n2 & 7)) << 3)];
            const f16x8 v1 = *(const f16x8*)&lV[n2 * 64 + (((4 + quad) ^ (n2 & 7)) << 3)];
            accO[0][nt2] = MFMA16(ap[0][0], v0, accO[0][nt2]);
            accO[0][nt2] = MFMA16(ap[0][1], v1, accO[0][nt2]);
            accO[1][nt2] = MFMA16(ap[1][0], v0, accO[1][nt2]);
            accO[1][nt2] = MFMA16(ap[1][1], v1, accO[1][nt2]);
        }
        __syncthreads();
    }

#pragma unroll
    for (int mt = 0; mt < 2; ++mt)
#pragma unroll
        for (int r2 = 0; r2 < 4; ++r2) {
            float v = l_acc[mt][r2];
            v += __shfl_xor(v, 1);
            v += __shfl_xor(v, 2);
            v += __shfl_xor(v, 4);
            v += __shfl_xor(v, 8);
            if (l15 == 0)
                atomicAdd(&lsum[h * LQ + q0 + mt * 16 + quad * 4 + r2], v);
        }
    float* Cp = Opart + (long)kc * LQ * CDIM + h * HDIM;
#pragma unroll
    for (int mt = 0; mt < 2; ++mt)
#pragma unroll
        for (int nt2 = 0; nt2 < 8; ++nt2)
#pragma unroll
            for (int rx = 0; rx < 4; ++rx)
                Cp[(long)(q0 + mt * 16 + quad * 4 + rx) * CDIM + nt2 * 16 + l15] =
                    accO[mt][nt2][rx];
}

// ---------------------------------------------------------------------------
// merge: a2[q][c] = (Op0+Op1)[q][c] / lsum[c>>7][q]   (fp16 out)
// ---------------------------------------------------------------------------
__global__ __launch_bounds__(256) void merge_o(
    const float* __restrict__ Op, const float* __restrict__ lsum,
    __half* __restrict__ a2)
{
    const int row = blockIdx.x;
    const int c0  = threadIdx.x * 8;
    const float inv = 1.0f / lsum[(c0 >> 7) * LQ + row];
    const float* p0 = Op + (long)row * CDIM + c0;
    const float* p1 = p0 + (long)LQ * CDIM;
    union { f16x8 v; _Float16 e[8]; } o;
#pragma unroll
    for (int j = 0; j < 8; ++j)
        o.e[j] = (_Float16)((p0[j] + p1[j]) * inv);
    *(f16x8*)&a2[(long)row * 4096 + c0] = o.v;
}

// ---------------------------------------------------------------------------
// ONE prep launch: 6 casts + Wo pack + sw2^T + sin features + lsum zero.
// ---------------------------------------------------------------------------
__global__ __launch_bounds__(256) void prep_all(
    const float* __restrict__ h2, const float* __restrict__ h0,
    const float* __restrict__ h1, const float* __restrict__ Wq,
    const float* __restrict__ Wk, const float* __restrict__ Wv,
    const float* __restrict__ Wo, const float* __restrict__ sw1,
    const float* __restrict__ sb1, const float* __restrict__ sw2,
    __half* __restrict__ xq, __half* __restrict__ xkv,
    __half* __restrict__ wqh, __half* __restrict__ wkv,
    __half* __restrict__ a2, __half* __restrict__ b2,
    float* __restrict__ lsum)
{
    __shared__ float t[64][65];
    const int blk = blockIdx.x;
    const int tid = threadIdx.x;
    if (blk < 24576) {
        const long i = ((long)blk * 256 + tid) << 2;
        const int chunk = (int)(i >> 22);
        const long off = i & 4194303;
        const float* s; __half* d;
        switch (chunk) {
            case 0:  s = h2; d = xq;            break;
            case 1:  s = h0; d = xkv;           break;
            case 2:  s = h1; d = xkv + 4194304; break;
            case 3:  s = Wq; d = wqh;           break;
            case 4:  s = Wk; d = wkv;           break;
            default: s = Wv; d = wkv + 4194304; break;
        }
        const float4 v = *(const float4*)&s[off];
        f16x4 o;
        o[0] = (_Float16)v.x; o[1] = (_Float16)v.y;
        o[2] = (_Float16)v.z; o[3] = (_Float16)v.w;
        *(f16x4*)&d[off] = o;
    } else if (blk < 28672) {
        const int i = ((blk - 24576) * 256 + tid) << 2;
        const int o = i >> 11, c = i & 2047;
        const float4 v = *(const float4*)&Wo[i];
        f16x4 w4;
        w4[0] = (_Float16)v.x; w4[1] = (_Float16)v.y;
        w4[2] = (_Float16)v.z; w4[3] = (_Float16)v.w;
        *(f16x4*)&b2[((long)o << 12) + c] = w4;
    } else if (blk < 29696) {
        const int lb = blk - 28672;
        const long r0 = (long)(lb & 31) * 64;
        const long c0 = (long)(lb >> 5) * 64;
        const int tj = tid & 63;
        const int ti = tid >> 6;
#pragma unroll
        for (int it = 0; it < 16; ++it) {
            const int i = it * 4 + ti;
            t[i][tj] = sw2[(r0 + i) * 2048 + c0 + tj];
        }
        __syncthreads();
#pragma unroll
        for (int it = 0; it < 16; ++it) {
            const int i = it * 4 + ti;
            b2[(c0 + i) * 4096 + 2048 + r0 + tj] = __float2half(t[tj][i]);
        }
    } else if (blk < 33792) {
        const int i = ((blk - 29696) * 256 + tid) << 2;
        const int l = i >> 11, c = i & 2047;
        const float coord = -1.0f + (2.0f / 2047.0f) * (float)l;
        const float4 w = *(const float4*)&sw1[c];
        const float4 b = *(const float4*)&sb1[c];
        f16x4 o;
        o[0] = (_Float16)__sinf(30.0f * (coord * w.x + b.x));
        o[1] = (_Float16)__sinf(30.0f * (coord * w.y + b.y));
        o[2] = (_Float16)__sinf(30.0f * (coord * w.z + b.z));
        o[3] = (_Float16)__sinf(30.0f * (coord * w.w + b.w));
        *(f16x4*)&a2[((long)l << 12) + 2048 + c] = o;
    } else {
        const int i = ((blk - 33792) * 256 + tid) << 2;
        *(float4*)&lsum[i] = (float4){0.f, 0.f, 0.f, 0.f};
    }
}

__global__ __launch_bounds__(256) void final_norm(
    const float* __restrict__ out2, const float* __restrict__ x,
    const float* __restrict__ sb2, const float* __restrict__ on_w,
    float* __restrict__ y)
{
    const int row = blockIdx.x;
    const float* o0 = out2 + (long)row * CDIM;
    const float* o1 = o0 + (long)LQ * CDIM;
    float4 v[2];
    float ss = 0.f;
#pragma unroll
    for (int i = 0; i < 2; ++i) {
        const int c = threadIdx.x * 4 + i * 1024;
        const float4 a = *(const float4*)&o0[c];
        const float4 b = *(const float4*)&o1[c];
        const float4 s = *(const float4*)&sb2[c];
        float4 tv;
        tv.x = a.x + b.x + s.x; tv.y = a.y + b.y + s.y;
        tv.z = a.z + b.z + s.z; tv.w = a.w + b.w + s.w;
        v[i] = tv;
        ss += tv.x * tv.x + tv.y * tv.y + tv.z * tv.z + tv.w * tv.w;
    }
#pragma unroll
    for (int off = 1; off < 64; off <<= 1) ss += __shfl_xor(ss, off);
    __shared__ float red[4];
    const int lane = threadIdx.x & 63, wv = threadIdx.x >> 6;
    if (lane == 0) red[wv] = ss;
    __syncthreads();
    const float tot = red[0] + red[1] + red[2] + red[3];
    const float rn = rsqrtf(tot * (1.0f / 2048.0f) + 1e-6f);
#pragma unroll
    for (int i = 0; i < 2; ++i) {
        const int c = threadIdx.x * 4 + i * 1024;
        const float4 xr = *(const float4*)&x[(long)row * CDIM + c];
        const float4 wv4 = *(const float4*)&on_w[c];
        float4 o;
        o.x = xr.x + v[i].x * rn * wv4.x;
        o.y = xr.y + v[i].y * rn * wv4.y;
        o.z = xr.z + v[i].z * rn * wv4.z;
        o.w = xr.w + v[i].w * rn * wv4.w;
        *(float4*)&y[(long)row * CDIM + c] = o;
    }
}

// ---------------------------------------------------------------------------
extern "C" void kernel_launch(void* const* d_in, const int* in_sizes, int n_in,
                              void* d_out, int out_size, void* d_ws, size_t ws_size,
                              hipStream_t stream) {
    const float* x    = (const float*)d_in[0];
    const float* h0   = (const float*)d_in[1];
    const float* h1   = (const float*)d_in[2];
    const float* h2   = (const float*)d_in[3];
    const float* Wq   = (const float*)d_in[4];
    const float* Wk   = (const float*)d_in[5];
    const float* Wv   = (const float*)d_in[6];
    const float* Wo   = (const float*)d_in[7];
    const float* qn_w = (const float*)d_in[8];
    const float* kn_w = (const float*)d_in[9];
    const float* on_w = (const float*)d_in[10];
    const float* sw1  = (const float*)d_in[11];
    const float* sb1  = (const float*)d_in[12];
    const float* sw2  = (const float*)d_in[13];
    const float* sb2  = (const float*)d_in[14];
    float* y = (float*)d_out;

    const size_t MB = 1ull << 20;
    char* w = (char*)d_ws;
    __half* xq  = (__half*)(w);             //  8 MB  h2 fp16
    __half* xkv = (__half*)(w + 8 * MB);    // 16 MB  [h0;h1] fp16
    __half* wqh = (__half*)(w + 24 * MB);   //  8 MB  Wq fp16
    __half* wkv = (__half*)(w + 32 * MB);   // 16 MB  [Wk;Wv] fp16
    __half* qf  = (__half*)(w + 48 * MB);   //  8 MB  Q proj, normed+roped
    __half* kvf = (__half*)(w + 56 * MB);   // 32 MB  K normed (cols 0..2047)
    __half* vT  = (__half*)(w + 88 * MB);   // 16 MB  V transposed (2048x4096)
    __half* a2  = (__half*)(w + 104 * MB);  // 16 MB  [attn_out | sin_feat]
    __half* b2  = (__half*)(w + 120 * MB);  // 16 MB  [Wo | sw2^T]
    float* lsum  = (float*)(w + 136 * MB);  // 128 KB (zeroed in prep)
    float* Opart = (float*)(w);             // 32 MB  overlays xq/xkv (dead)
    float* out2  = (float*)(w);             // 32 MB  [2] split-K partials
    (void)in_sizes; (void)n_in; (void)out_size; (void)ws_size;

    prep_all<<<33824, 256, 0, stream>>>(h2, h0, h1, Wq, Wk, Wv, Wo, sw1, sb1,
                                        sw2, xq, xkv, wqh, wkv, a2, b2, lsum);

    // KV projection: 8-phase 256² kernel (norm+rope K, transposed V)
    gemm_kv8<<<256, 512, 0, stream>>>(xkv, wkv, kvf, vT, kn_w);
    // Q projection: proven 128² kernel (norm+rope, log2e/sqrt(D) pre-scale)
    gemm_q<<<256, 256, 0, stream>>>(xq, wqh, qf, qn_w);

    attn_tile<<<dim3(16, 32), 256, 0, stream>>>(qf, kvf, vT, Opart, lsum);
    merge_o<<<2048, 256, 0, stream>>>(Opart, lsum, a2);

    gemm_sk<<<dim3(16, 16, 2), 256, 0, stream>>>(a2, b2, out2, 4096, 4096, 2048, 2048);
    final_norm<<<2048, 256, 0, stream>>>(out2, x, sb2, on_w, y);
}

// Round 10
// 430.629 us; speedup vs baseline: 1.0842x; 1.0117x over previous
//
#include <hip/hip_runtime.h>
#include <hip/hip_fp16.h>

// Problem constants: B=1, L=2048, C=2048, H=16, D=128, keys = 2L = 4096
#define LQ 2048
#define CDIM 2048
#define NHEAD 16
#define HDIM 128
#define LKEY 4096

typedef _Float16 f16x8 __attribute__((ext_vector_type(8)));
typedef _Float16 f16x4 __attribute__((ext_vector_type(4)));
typedef float f32x4 __attribute__((ext_vector_type(4)));

#define GLOAD_LDS16(g, s) __builtin_amdgcn_global_load_lds( \
    (const __attribute__((address_space(1))) void*)(g),     \
    (__attribute__((address_space(3))) void*)(s), 16, 0, 0)

#define MFMA16(a, b, c) __builtin_amdgcn_mfma_f32_16x16x32_f16(a, b, c, 0, 0, 0)

__device__ __forceinline__ void storeC(float* p, float v) { *p = v; }
__device__ __forceinline__ void storeC(__half* p, float v) { *p = __float2half(v); }

// ---------------------------------------------------------------------------
// Shared 128x128 GEMM body (m97 structure) — MODE 0 plain store.
// Used by gemm_sk (final GEMM) and gemm_skq (Q projection split-K).
// ---------------------------------------------------------------------------
template <int MODE, typename OutT>
__device__ __forceinline__ void gemm_body(
    __half* smem,
    const __half* __restrict__ A, const __half* __restrict__ B,
    OutT* __restrict__ C, int lda, int ldb, int ldc, int K,
    int bmA, int bmC, int bn)
{
    __half* lA = smem;
    __half* lB = smem + 8192;
    const int tid  = threadIdx.x;
    const int lane = tid & 63;
    const int wave = tid >> 6;
    const int r = tid >> 3;
    const int g = tid & 7;
    const __half* gA = A + (long)(bmA * 128 + r) * lda + ((g ^ (r & 7)) << 3);
    const __half* gB = B + (long)(bn * 128 + r) * ldb + ((g ^ (r & 7)) << 3);
    __half* lAp = lA + tid * 8;
    __half* lBp = lB + tid * 8;
    const int wr = (wave & 1) << 6;
    const int wc = (wave >> 1) << 6;
    const int l15 = lane & 15, quad = lane >> 4;

    f32x4 acc[4][4] = {};

    for (int kt = 0; kt < K; kt += 64) {
#pragma unroll
        for (int i = 0; i < 4; ++i) {
            GLOAD_LDS16(gA + (long)i * 32 * lda, lAp + i * 2048);
            GLOAD_LDS16(gB + (long)i * 32 * ldb, lBp + i * 2048);
        }
        gA += 64; gB += 64;
        __syncthreads();
#pragma unroll
        for (int kk = 0; kk < 2; ++kk) {
            f16x8 af[4], bfr[4];
#pragma unroll
            for (int mi = 0; mi < 4; ++mi) {
                const int m = wr + mi * 16 + l15;
                const int kg = kk * 4 + quad;
                af[mi] = *(const f16x8*)&lA[m * 64 + ((kg ^ (m & 7)) << 3)];
            }
#pragma unroll
            for (int ni = 0; ni < 4; ++ni) {
                const int n = wc + ni * 16 + l15;
                const int kg = kk * 4 + quad;
                bfr[ni] = *(const f16x8*)&lB[n * 64 + ((kg ^ (n & 7)) << 3)];
            }
#pragma unroll
            for (int mi = 0; mi < 4; ++mi)
#pragma unroll
                for (int ni = 0; ni < 4; ++ni)
                    acc[mi][ni] = MFMA16(af[mi], bfr[ni], acc[mi][ni]);
        }
        __syncthreads();
    }

    const int row0 = bmC * 128 + wr + quad * 4;
    const int col0 = bn * 128 + wc + l15;
#pragma unroll
    for (int mi = 0; mi < 4; ++mi)
#pragma unroll
        for (int ni = 0; ni < 4; ++ni)
#pragma unroll
            for (int rx = 0; rx < 4; ++rx)
                storeC(&C[(long)(row0 + mi * 16 + rx) * ldc + col0 + ni * 16],
                       acc[mi][ni][rx]);
}

// ---------------------------------------------------------------------------
// 8-phase 256x256 KV projection GEMM (proven in v10, byte-identical).
// ---------------------------------------------------------------------------
__device__ __forceinline__ void stage_half(
    const __half* __restrict__ M, long row0, int T, char* lds, int slot, int tid)
{
    char* dst = lds + slot * 16384 + tid * 16;
    const int r = tid >> 3;            // 0..63
    const int g = tid & 7;
    const int co = T * 64 + ((g ^ (r & 7)) << 3);
    GLOAD_LDS16(M + (row0 + r) * 2048 + co, dst);
    GLOAD_LDS16(M + (row0 + r + 64) * 2048 + co, dst + 8192);  // (r+64)&7 == r&7
}

__global__ __launch_bounds__(512, 1) void gemm_kv8(
    const __half* __restrict__ A,   // xkv 4096x2048
    const __half* __restrict__ B,   // wkv 4096x2048
    __half* __restrict__ Ckv,       // kvf 4096x4096 (K half: cols 0..2047)
    __half* __restrict__ vT,        // 2048x4096
    const float* __restrict__ kn_w)
{
    __shared__ __align__(16) char LDS[131072];
    const int tid  = threadIdx.x;
    const int lane = tid & 63;
    const int wave = tid >> 6;
    const int wm = wave >> 2;           // 0..1
    const int wn = wave & 3;            // 0..3
    const int l15 = lane & 15, quad = lane >> 4;
    const int bm = blockIdx.x & 15;
    const int bn = blockIdx.x >> 4;
    const long arow = (long)bm * 256;
    const long brow = (long)bn * 256;

    f32x4 acc[8][4] = {};

    stage_half(A, arow,       0, LDS, 0, tid);
    stage_half(A, arow + 128, 0, LDS, 1, tid);
    stage_half(B, brow,       0, LDS, 4, tid);
    stage_half(B, brow + 128, 0, LDS, 5, tid);

    for (int tt = 0; tt < 32; ++tt) {
        const int buf = tt & 1, sbuf = buf ^ 1;
        const int Tn = (tt < 31) ? tt + 1 : 31;
        const __half* As = (const __half*)(LDS + (buf * 2 + wm) * 16384);
        const __half* Bs = (const __half*)(LDS + (4 + buf * 2 + (wn >> 1)) * 16384);
        f16x8 bq[4][2];
#pragma unroll
        for (int q = 0; q < 4; ++q) {
            if (q == 0)      stage_half(A, arow,       Tn, LDS, 0 + sbuf * 2, tid);
            else if (q == 1) stage_half(A, arow + 128, Tn, LDS, 1 + sbuf * 2, tid);
            else if (q == 2) stage_half(B, brow,       Tn, LDS, 4 + sbuf * 2, tid);
            else             stage_half(B, brow + 128, Tn, LDS, 5 + sbuf * 2, tid);
            if (q == 0)
                asm volatile("s_waitcnt vmcnt(2)" ::: "memory");
            __builtin_amdgcn_s_barrier();
            __builtin_amdgcn_sched_barrier(0);
            if (q == 0) {
#pragma unroll
                for (int ni = 0; ni < 4; ++ni) {
                    const int rb = ((wn & 1) << 6) + ni * 16 + l15;
#pragma unroll
                    for (int ks = 0; ks < 2; ++ks)
                        bq[ni][ks] = *(const f16x8*)
                            &Bs[rb * 64 + (((ks * 4 + quad) ^ (rb & 7)) << 3)];
                }
            }
            f16x8 av[2][2];
#pragma unroll
            for (int m2 = 0; m2 < 2; ++m2) {
                const int ra = (q * 2 + m2) * 16 + l15;
#pragma unroll
                for (int ks = 0; ks < 2; ++ks)
                    av[m2][ks] = *(const f16x8*)
                        &As[ra * 64 + (((ks * 4 + quad) ^ (ra & 7)) << 3)];
            }
            __builtin_amdgcn_s_setprio(1);
#pragma unroll
            for (int m2 = 0; m2 < 2; ++m2)
#pragma unroll
                for (int ni = 0; ni < 4; ++ni) {
                    acc[q * 2 + m2][ni] = MFMA16(av[m2][0], bq[ni][0], acc[q * 2 + m2][ni]);
                    acc[q * 2 + m2][ni] = MFMA16(av[m2][1], bq[ni][1], acc[q * 2 + m2][ni]);
                }
            __builtin_amdgcn_s_setprio(0);
            __builtin_amdgcn_s_barrier();
            __builtin_amdgcn_sched_barrier(0);
        }
    }

    __syncthreads();

    if (bn < 8) {
        __half* sT = (__half*)LDS;
#pragma unroll
        for (int mi = 0; mi < 8; ++mi)
#pragma unroll
            for (int ni = 0; ni < 4; ++ni)
#pragma unroll
                for (int rx = 0; rx < 4; ++rx)
                    sT[(wm * 128 + mi * 16 + quad * 4 + rx) * 256 +
                       wn * 64 + ni * 16 + l15] = (_Float16)acc[mi][ni][rx];
        __syncthreads();
        const int row = tid >> 1;
        const int hs  = tid & 1;
        const __half* rp = sT + row * 256 + hs * 128;
        f16x8 xv[16];
#pragma unroll
        for (int j = 0; j < 16; ++j) xv[j] = *(const f16x8*)&rp[j * 8];
        float ss = 0.f;
#pragma unroll
        for (int j = 0; j < 16; ++j)
#pragma unroll
            for (int e = 0; e < 8; ++e) {
                const float v = (float)xv[j][e];
                ss += v * v;
            }
        const float rn = rsqrtf(ss * (1.0f / 128.0f) + 1e-6f);
        const long R = arow + row;
        const float depth = (R < 2048) ? 0.f : 1.f;
        __half* op = Ckv + R * 4096 + bn * 256 + hs * 128;
#pragma unroll
        for (int j = 0; j < 8; ++j) {
            union { f16x8 v; _Float16 e[8]; } o1, o2;
#pragma unroll
            for (int e = 0; e < 8; ++e) {
                const int d = j * 8 + e;
                const float x1 = (float)xv[j][e]     * rn * kn_w[d];
                const float x2 = (float)xv[j + 8][e] * rn * kn_w[d + 64];
                const float ang = depth * exp2f(-(float)d * 0.20762050593045702f);
                float sn, cs;
                __sincosf(ang, &sn, &cs);
                o1.e[e] = (_Float16)(x1 * cs - x2 * sn);
                o2.e[e] = (_Float16)(x1 * sn + x2 * cs);
            }
            *(f16x8*)&op[j * 8]      = o1.v;
            *(f16x8*)&op[64 + j * 8] = o2.v;
        }
    } else {
#pragma unroll
        for (int mi = 0; mi < 8; ++mi)
#pragma unroll
            for (int ni = 0; ni < 4; ++ni)
#pragma unroll
                for (int rx = 0; rx < 4; ++rx) {
                    const int d = (bn - 8) * 256 + wn * 64 + ni * 16 + l15;
                    const long key = arow + wm * 128 + mi * 16 + quad * 4 + rx;
                    vT[(long)d * LKEY + key] = __float2half(acc[mi][ni][rx]);
                }
    }
}

// ---------------------------------------------------------------------------
// Q projection, split-K x2 (fp32 partials): 512 blocks = 2/CU — the measured-
// good regime (v10's single-pass gemm_q at 256 blocks = 1 wave/SIMD was the
// v3 latency-exposed regime, est ~54us). Partials land in two dead 16MB
// workspace regions (xkv, wkv — both dead after gemm_kv8).
// ---------------------------------------------------------------------------
__global__ __launch_bounds__(256, 2) void gemm_skq(
    const __half* __restrict__ A, const __half* __restrict__ Bq,
    float* __restrict__ qp0, float* __restrict__ qp1)
{
    __shared__ __align__(16) __half smem[16384];
    const int z = blockIdx.z;
    float* C = z ? qp1 : qp0;
    gemm_body<0, float>(smem, A + z * 1024, Bq + z * 1024, C,
                        2048, 2048, 2048, 1024,
                        blockIdx.x, blockIdx.x, blockIdx.y);
}

// ---------------------------------------------------------------------------
// Q norm+rope pass: sum the 2 partials, rmsnorm per (row,head), rope depth=2,
// log2(e)/sqrt(D) pre-scale, fp16 out. 2 rows/block; 8 threads per head.
// ---------------------------------------------------------------------------
__global__ __launch_bounds__(256) void normrope_q(
    const float* __restrict__ qp0, const float* __restrict__ qp1,
    __half* __restrict__ qf, const float* __restrict__ qn_w)
{
    const int tid  = threadIdx.x;
    const int row  = blockIdx.x * 2 + (tid >> 7);
    const int head = (tid >> 3) & 15;
    const int sub  = tid & 7;
    const long base = (long)row * 2048 + head * 128 + sub * 8;

    const float4 p0a = *(const float4*)&qp0[base];
    const float4 p0b = *(const float4*)&qp0[base + 4];
    const float4 p1a = *(const float4*)&qp1[base];
    const float4 p1b = *(const float4*)&qp1[base + 4];
    const float4 q0a = *(const float4*)&qp0[base + 64];
    const float4 q0b = *(const float4*)&qp0[base + 68];
    const float4 q1a = *(const float4*)&qp1[base + 64];
    const float4 q1b = *(const float4*)&qp1[base + 68];
    float x1[8] = {p0a.x + p1a.x, p0a.y + p1a.y, p0a.z + p1a.z, p0a.w + p1a.w,
                   p0b.x + p1b.x, p0b.y + p1b.y, p0b.z + p1b.z, p0b.w + p1b.w};
    float x2[8] = {q0a.x + q1a.x, q0a.y + q1a.y, q0a.z + q1a.z, q0a.w + q1a.w,
                   q0b.x + q1b.x, q0b.y + q1b.y, q0b.z + q1b.z, q0b.w + q1b.w};

    float ss = 0.f;
#pragma unroll
    for (int j = 0; j < 8; ++j) ss += x1[j] * x1[j] + x2[j] * x2[j];
    ss += __shfl_xor(ss, 1);
    ss += __shfl_xor(ss, 2);
    ss += __shfl_xor(ss, 4);
    const float rn = rsqrtf(ss * (1.0f / 128.0f) + 1e-6f);

    union { f16x8 v; _Float16 e[8]; } o1, o2;
#pragma unroll
    for (int j = 0; j < 8; ++j) {
        const int d = sub * 8 + j;
        const float a1 = x1[j] * rn * qn_w[d];
        const float a2 = x2[j] * rn * qn_w[d + 64];
        const float ang = 2.0f * exp2f(-(float)d * 0.20762050593045702f);
        float sn, cs;
        __sincosf(ang, &sn, &cs);
        o1.e[j] = (_Float16)((a1 * cs - a2 * sn) * 0.12751743f);
        o2.e[j] = (_Float16)((a1 * sn + a2 * cs) * 0.12751743f);
    }
    __half* op = qf + base;
    *(f16x8*)&op[0]  = o1.v;
    *(f16x8*)&op[64] = o2.v;
}

// ---------------------------------------------------------------------------
// Split-K x2 final GEMM: grid (16,16,2) = 512 blocks, (256,2) proven config.
// ---------------------------------------------------------------------------
__global__ __launch_bounds__(256, 2) void gemm_sk(
    const __half* __restrict__ A, const __half* __restrict__ B,
    float* __restrict__ C, int lda, int ldb, int ldc, int Khalf)
{
    __shared__ __align__(16) __half smem[16384];
    const int z = blockIdx.z;
    gemm_body<0, float>(smem, A + z * Khalf, B + z * Khalf,
                        C + (long)z * LQ * CDIM,
                        lda, ldb, ldc, Khalf, blockIdx.x, blockIdx.x, blockIdx.y);
}

// ---------------------------------------------------------------------------
// Fused attention tile kernel (max-free softmax, log2-domain scores).
// v9 structure: v1 inner loop + XCD-affinity remap. Unchanged (pinned ~96us
// across 7 variants; FETCH 20.5MB with swizzle).
// ---------------------------------------------------------------------------
__global__ __launch_bounds__(256, 2) void attn_tile(
    const __half* __restrict__ Qf,
    const __half* __restrict__ Kf,
    const __half* __restrict__ Vt,
    float* __restrict__ Opart,
    float* __restrict__ lsum)
{
    __shared__ __align__(16) __half lK[64 * 128];
    __shared__ __align__(16) __half lV[128 * 64];
    __shared__ __align__(16) __half pL[4 * 2 * 16 * 76];

    const int tid  = threadIdx.x;
    const int lane = tid & 63;
    const int wave = tid >> 6;
    const int l15  = lane & 15;
    const int quad = lane >> 4;
    const int lin = blockIdx.y * 16 + blockIdx.x;
    const int hkc = (lin & 7) * 4 + ((lin >> 3) & 3);
    const int qt  = lin >> 5;
    const int h   = hkc >> 1;
    const int kc  = hkc & 1;
    const int q0  = qt * 128 + wave * 32;

    f16x8 aq[2][4];
#pragma unroll
    for (int mt = 0; mt < 2; ++mt)
#pragma unroll
        for (int ks = 0; ks < 4; ++ks)
            aq[mt][ks] = *(const f16x8*)&Qf[(long)(q0 + mt * 16 + l15) * CDIM +
                                            h * HDIM + ks * 32 + quad * 8];

    const int rK = tid >> 4;
    const int gK = tid & 15;
    const __half* srcK = Kf + (long)(kc * 2048 + rK) * 4096 + h * HDIM +
                         ((gK ^ (rK & 15)) << 3);
    const int rV = tid >> 3;
    const int gV = tid & 7;
    const __half* srcV = Vt + (long)(h * HDIM + rV) * (long)LKEY + kc * 2048 +
                         ((gV ^ (rV & 7)) << 3);
    __half* dstK = lK + tid * 8;
    __half* dstV = lV + tid * 8;

    f32x4 accO[2][8] = {};
    f32x4 l_acc[2] = {};

    for (int st = 0; st < 32; ++st) {
#pragma unroll
        for (int i = 0; i < 4; ++i) {
            GLOAD_LDS16(srcK + (long)(st * 64 + i * 16) * 4096, dstK + i * 2048);
            GLOAD_LDS16(srcV + (long)i * 32 * LKEY + st * 64, dstV + i * 2048);
        }
        __syncthreads();
        f32x4 s[2][4];
#pragma unroll
        for (int mt = 0; mt < 2; ++mt)
#pragma unroll
            for (int nt = 0; nt < 4; ++nt)
                s[mt][nt] = (f32x4){-10.f, -10.f, -10.f, -10.f};
#pragma unroll
        for (int nt = 0; nt < 4; ++nt) {
            const int n = nt * 16 + l15;
#pragma unroll
            for (int ks = 0; ks < 4; ++ks) {
                const f16x8 kf = *(const f16x8*)
                    &lK[n * 128 + (((ks * 4 + quad) ^ (n & 15)) << 3)];
                s[0][nt] = MFMA16(aq[0][ks], kf, s[0][nt]);
                s[1][nt] = MFMA16(aq[1][ks], kf, s[1][nt]);
            }
        }
#pragma unroll
        for (int mt = 0; mt < 2; ++mt)
#pragma unroll
            for (int nt = 0; nt < 4; ++nt)
#pragma unroll
                for (int r2 = 0; r2 < 4; ++r2) {
                    const float p = __builtin_amdgcn_exp2f(s[mt][nt][r2]);
                    l_acc[mt][r2] += p;
                    pL[((wave * 2 + mt) * 16 + quad * 4 + r2) * 76 +
                       nt * 16 + l15] = __float2half(p);
                }
        f16x8 ap[2][2];
#pragma unroll
        for (int mt = 0; mt < 2; ++mt) {
            ap[mt][0] = *(const f16x8*)&pL[((wave * 2 + mt) * 16 + l15) * 76 + quad * 8];
            ap[mt][1] = *(const f16x8*)&pL[((wave * 2 + mt) * 16 + l15) * 76 + 32 + quad * 8];
        }
#pragma unroll
        for (int nt2 = 0; nt2 < 8; ++nt2) {
            const int n2 = nt2 * 16 + l15;
            const f16x8 v0 = *(const f16x8*)&lV[n2 * 64 + ((quad ^ (n2 & 7)) << 3)];
            const f16x8 v1 = *(const f16x8*)&lV[n2 * 64 + (((4 + quad) ^ (n2 & 7)) << 3)];
            accO[0][nt2] = MFMA16(ap[0][0], v0, accO[0][nt2]);
            accO[0][nt2] = MFMA16(ap[0][1], v1, accO[0][nt2]);
            accO[1][nt2] = MFMA16(ap[1][0], v0, accO[1][nt2]);
            accO[1][nt2] = MFMA16(ap[1][1], v1, accO[1][nt2]);
        }
        __syncthreads();
    }

#pragma unroll
    for (int mt = 0; mt < 2; ++mt)
#pragma unroll
        for (int r2 = 0; r2 < 4; ++r2) {
            float v = l_acc[mt][r2];
            v += __shfl_xor(v, 1);
            v += __shfl_xor(v, 2);
            v += __shfl_xor(v, 4);
            v += __shfl_xor(v, 8);
            if (l15 == 0)
                atomicAdd(&lsum[h * LQ + q0 + mt * 16 + quad * 4 + r2], v);
        }
    float* Cp = Opart + (long)kc * LQ * CDIM + h * HDIM;
#pragma unroll
    for (int mt = 0; mt < 2; ++mt)
#pragma unroll
        for (int nt2 = 0; nt2 < 8; ++nt2)
#pragma unroll
            for (int rx = 0; rx < 4; ++rx)
                Cp[(long)(q0 + mt * 16 + quad * 4 + rx) * CDIM + nt2 * 16 + l15] =
                    accO[mt][nt2][rx];
}

// ---------------------------------------------------------------------------
// merge: a2[q][c] = (Op0+Op1)[q][c] / lsum[c>>7][q]   (fp16 out)
// ---------------------------------------------------------------------------
__global__ __launch_bounds__(256) void merge_o(
    const float* __restrict__ Op, const float* __restrict__ lsum,
    __half* __restrict__ a2)
{
    const int row = blockIdx.x;
    const int c0  = threadIdx.x * 8;
    const float inv = 1.0f / lsum[(c0 >> 7) * LQ + row];
    const float* p0 = Op + (long)row * CDIM + c0;
    const float* p1 = p0 + (long)LQ * CDIM;
    union { f16x8 v; _Float16 e[8]; } o;
#pragma unroll
    for (int j = 0; j < 8; ++j)
        o.e[j] = (_Float16)((p0[j] + p1[j]) * inv);
    *(f16x8*)&a2[(long)row * 4096 + c0] = o.v;
}

// ---------------------------------------------------------------------------
// ONE prep launch: 6 casts + Wo pack + sw2^T + sin features + lsum zero.
// ---------------------------------------------------------------------------
__global__ __launch_bounds__(256) void prep_all(
    const float* __restrict__ h2, const float* __restrict__ h0,
    const float* __restrict__ h1, const float* __restrict__ Wq,
    const float* __restrict__ Wk, const float* __restrict__ Wv,
    const float* __restrict__ Wo, const float* __restrict__ sw1,
    const float* __restrict__ sb1, const float* __restrict__ sw2,
    __half* __restrict__ xq, __half* __restrict__ xkv,
    __half* __restrict__ wqh, __half* __restrict__ wkv,
    __half* __restrict__ a2, __half* __restrict__ b2,
    float* __restrict__ lsum)
{
    __shared__ float t[64][65];
    const int blk = blockIdx.x;
    const int tid = threadIdx.x;
    if (blk < 24576) {
        const long i = ((long)blk * 256 + tid) << 2;
        const int chunk = (int)(i >> 22);
        const long off = i & 4194303;
        const float* s; __half* d;
        switch (chunk) {
            case 0:  s = h2; d = xq;            break;
            case 1:  s = h0; d = xkv;           break;
            case 2:  s = h1; d = xkv + 4194304; break;
            case 3:  s = Wq; d = wqh;           break;
            case 4:  s = Wk; d = wkv;           break;
            default: s = Wv; d = wkv + 4194304; break;
        }
        const float4 v = *(const float4*)&s[off];
        f16x4 o;
        o[0] = (_Float16)v.x; o[1] = (_Float16)v.y;
        o[2] = (_Float16)v.z; o[3] = (_Float16)v.w;
        *(f16x4*)&d[off] = o;
    } else if (blk < 28672) {
        const int i = ((blk - 24576) * 256 + tid) << 2;
        const int o = i >> 11, c = i & 2047;
        const float4 v = *(const float4*)&Wo[i];
        f16x4 w4;
        w4[0] = (_Float16)v.x; w4[1] = (_Float16)v.y;
        w4[2] = (_Float16)v.z; w4[3] = (_Float16)v.w;
        *(f16x4*)&b2[((long)o << 12) + c] = w4;
    } else if (blk < 29696) {
        const int lb = blk - 28672;
        const long r0 = (long)(lb & 31) * 64;
        const long c0 = (long)(lb >> 5) * 64;
        const int tj = tid & 63;
        const int ti = tid >> 6;
#pragma unroll
        for (int it = 0; it < 16; ++it) {
            const int i = it * 4 + ti;
            t[i][tj] = sw2[(r0 + i) * 2048 + c0 + tj];
        }
        __syncthreads();
#pragma unroll
        for (int it = 0; it < 16; ++it) {
            const int i = it * 4 + ti;
            b2[(c0 + i) * 4096 + 2048 + r0 + tj] = __float2half(t[tj][i]);
        }
    } else if (blk < 33792) {
        const int i = ((blk - 29696) * 256 + tid) << 2;
        const int l = i >> 11, c = i & 2047;
        const float coord = -1.0f + (2.0f / 2047.0f) * (float)l;
        const float4 w = *(const float4*)&sw1[c];
        const float4 b = *(const float4*)&sb1[c];
        f16x4 o;
        o[0] = (_Float16)__sinf(30.0f * (coord * w.x + b.x));
        o[1] = (_Float16)__sinf(30.0f * (coord * w.y + b.y));
        o[2] = (_Float16)__sinf(30.0f * (coord * w.z + b.z));
        o[3] = (_Float16)__sinf(30.0f * (coord * w.w + b.w));
        *(f16x4*)&a2[((long)l << 12) + 2048 + c] = o;
    } else {
        const int i = ((blk - 33792) * 256 + tid) << 2;
        *(float4*)&lsum[i] = (float4){0.f, 0.f, 0.f, 0.f};
    }
}

__global__ __launch_bounds__(256) void final_norm(
    const float* __restrict__ out2, const float* __restrict__ x,
    const float* __restrict__ sb2, const float* __restrict__ on_w,
    float* __restrict__ y)
{
    const int row = blockIdx.x;
    const float* o0 = out2 + (long)row * CDIM;
    const float* o1 = o0 + (long)LQ * CDIM;
    float4 v[2];
    float ss = 0.f;
#pragma unroll
    for (int i = 0; i < 2; ++i) {
        const int c = threadIdx.x * 4 + i * 1024;
        const float4 a = *(const float4*)&o0[c];
        const float4 b = *(const float4*)&o1[c];
        const float4 s = *(const float4*)&sb2[c];
        float4 tv;
        tv.x = a.x + b.x + s.x; tv.y = a.y + b.y + s.y;
        tv.z = a.z + b.z + s.z; tv.w = a.w + b.w + s.w;
        v[i] = tv;
        ss += tv.x * tv.x + tv.y * tv.y + tv.z * tv.z + tv.w * tv.w;
    }
#pragma unroll
    for (int off = 1; off < 64; off <<= 1) ss += __shfl_xor(ss, off);
    __shared__ float red[4];
    const int lane = threadIdx.x & 63, wv = threadIdx.x >> 6;
    if (lane == 0) red[wv] = ss;
    __syncthreads();
    const float tot = red[0] + red[1] + red[2] + red[3];
    const float rn = rsqrtf(tot * (1.0f / 2048.0f) + 1e-6f);
#pragma unroll
    for (int i = 0; i < 2; ++i) {
        const int c = threadIdx.x * 4 + i * 1024;
        const float4 xr = *(const float4*)&x[(long)row * CDIM + c];
        const float4 wv4 = *(const float4*)&on_w[c];
        float4 o;
        o.x = xr.x + v[i].x * rn * wv4.x;
        o.y = xr.y + v[i].y * rn * wv4.y;
        o.z = xr.z + v[i].z * rn * wv4.z;
        o.w = xr.w + v[i].w * rn * wv4.w;
        *(float4*)&y[(long)row * CDIM + c] = o;
    }
}

// ---------------------------------------------------------------------------
extern "C" void kernel_launch(void* const* d_in, const int* in_sizes, int n_in,
                              void* d_out, int out_size, void* d_ws, size_t ws_size,
                              hipStream_t stream) {
    const float* x    = (const float*)d_in[0];
    const float* h0   = (const float*)d_in[1];
    const float* h1   = (const float*)d_in[2];
    const float* h2   = (const float*)d_in[3];
    const float* Wq   = (const float*)d_in[4];
    const float* Wk   = (const float*)d_in[5];
    const float* Wv   = (const float*)d_in[6];
    const float* Wo   = (const float*)d_in[7];
    const float* qn_w = (const float*)d_in[8];
    const float* kn_w = (const float*)d_in[9];
    const float* on_w = (const float*)d_in[10];
    const float* sw1  = (const float*)d_in[11];
    const float* sb1  = (const float*)d_in[12];
    const float* sw2  = (const float*)d_in[13];
    const float* sb2  = (const float*)d_in[14];
    float* y = (float*)d_out;

    const size_t MB = 1ull << 20;
    char* w = (char*)d_ws;
    __half* xq  = (__half*)(w);             //  8 MB  h2 fp16
    __half* xkv = (__half*)(w + 8 * MB);    // 16 MB  [h0;h1] fp16 (dead after kv8)
    __half* wqh = (__half*)(w + 24 * MB);   //  8 MB  Wq fp16
    __half* wkv = (__half*)(w + 32 * MB);   // 16 MB  [Wk;Wv] fp16 (dead after kv8)
    __half* qf  = (__half*)(w + 48 * MB);   //  8 MB  Q proj, normed+roped
    __half* kvf = (__half*)(w + 56 * MB);   // 32 MB  K normed (cols 0..2047)
    __half* vT  = (__half*)(w + 88 * MB);   // 16 MB  V transposed (2048x4096)
    __half* a2  = (__half*)(w + 104 * MB);  // 16 MB  [attn_out | sin_feat]
    __half* b2  = (__half*)(w + 120 * MB);  // 16 MB  [Wo | sw2^T]
    float* lsum  = (float*)(w + 136 * MB);  // 128 KB (zeroed in prep)
    float* qp0   = (float*)(w + 8 * MB);    // 16 MB  Q split-K partial 0 (xkv, dead)
    float* qp1   = (float*)(w + 32 * MB);   // 16 MB  Q split-K partial 1 (wkv, dead)
    float* Opart = (float*)(w);             // 32 MB  overlays xq/xkv (dead after skq)
    float* out2  = (float*)(w);             // 32 MB  [2] split-K partials
    (void)in_sizes; (void)n_in; (void)out_size; (void)ws_size;

    prep_all<<<33824, 256, 0, stream>>>(h2, h0, h1, Wq, Wk, Wv, Wo, sw1, sb1,
                                        sw2, xq, xkv, wqh, wkv, a2, b2, lsum);

    // KV projection: 8-phase 256² kernel (norm+rope K, transposed V)
    gemm_kv8<<<256, 512, 0, stream>>>(xkv, wkv, kvf, vT, kn_w);
    // Q projection: split-K x2 into fp32 partials (2 blocks/CU regime) + norm pass
    gemm_skq<<<dim3(16, 16, 2), 256, 0, stream>>>(xq, wqh, qp0, qp1);
    normrope_q<<<1024, 256, 0, stream>>>(qp0, qp1, qf, qn_w);

    attn_tile<<<dim3(16, 32), 256, 0, stream>>>(qf, kvf, vT, Opart, lsum);
    merge_o<<<2048, 256, 0, stream>>>(Opart, lsum, a2);

    gemm_sk<<<dim3(16, 16, 2), 256, 0, stream>>>(a2, b2, out2, 4096, 4096, 2048, 2048);
    final_norm<<<2048, 256, 0, stream>>>(out2, x, sb2, on_w, y);
}

// Round 11
// 422.226 us; speedup vs baseline: 1.1058x; 1.0199x over previous
//
#include <hip/hip_runtime.h>
#include <hip/hip_fp16.h>

// Problem constants: B=1, L=2048, C=2048, H=16, D=128, keys = 2L = 4096
#define LQ 2048
#define CDIM 2048
#define NHEAD 16
#define HDIM 128
#define LKEY 4096

typedef _Float16 f16x8 __attribute__((ext_vector_type(8)));
typedef _Float16 f16x4 __attribute__((ext_vector_type(4)));
typedef float f32x4 __attribute__((ext_vector_type(4)));

#define GLOAD_LDS16(g, s) __builtin_amdgcn_global_load_lds( \
    (const __attribute__((address_space(1))) void*)(g),     \
    (__attribute__((address_space(3))) void*)(s), 16, 0, 0)

#define MFMA16(a, b, c) __builtin_amdgcn_mfma_f32_16x16x32_f16(a, b, c, 0, 0, 0)

__device__ __forceinline__ void storeC(float* p, float v) { *p = v; }
__device__ __forceinline__ void storeC(__half* p, float v) { *p = __float2half(v); }

// ---------------------------------------------------------------------------
// Shared 128x128 GEMM body (m97 structure) — MODE 0 plain store.
// Used by gemm_sk (final GEMM) and gemm_skq (Q projection split-K).
// ---------------------------------------------------------------------------
template <int MODE, typename OutT>
__device__ __forceinline__ void gemm_body(
    __half* smem,
    const __half* __restrict__ A, const __half* __restrict__ B,
    OutT* __restrict__ C, int lda, int ldb, int ldc, int K,
    int bmA, int bmC, int bn)
{
    __half* lA = smem;
    __half* lB = smem + 8192;
    const int tid  = threadIdx.x;
    const int lane = tid & 63;
    const int wave = tid >> 6;
    const int r = tid >> 3;
    const int g = tid & 7;
    const __half* gA = A + (long)(bmA * 128 + r) * lda + ((g ^ (r & 7)) << 3);
    const __half* gB = B + (long)(bn * 128 + r) * ldb + ((g ^ (r & 7)) << 3);
    __half* lAp = lA + tid * 8;
    __half* lBp = lB + tid * 8;
    const int wr = (wave & 1) << 6;
    const int wc = (wave >> 1) << 6;
    const int l15 = lane & 15, quad = lane >> 4;

    f32x4 acc[4][4] = {};

    for (int kt = 0; kt < K; kt += 64) {
#pragma unroll
        for (int i = 0; i < 4; ++i) {
            GLOAD_LDS16(gA + (long)i * 32 * lda, lAp + i * 2048);
            GLOAD_LDS16(gB + (long)i * 32 * ldb, lBp + i * 2048);
        }
        gA += 64; gB += 64;
        __syncthreads();
#pragma unroll
        for (int kk = 0; kk < 2; ++kk) {
            f16x8 af[4], bfr[4];
#pragma unroll
            for (int mi = 0; mi < 4; ++mi) {
                const int m = wr + mi * 16 + l15;
                const int kg = kk * 4 + quad;
                af[mi] = *(const f16x8*)&lA[m * 64 + ((kg ^ (m & 7)) << 3)];
            }
#pragma unroll
            for (int ni = 0; ni < 4; ++ni) {
                const int n = wc + ni * 16 + l15;
                const int kg = kk * 4 + quad;
                bfr[ni] = *(const f16x8*)&lB[n * 64 + ((kg ^ (n & 7)) << 3)];
            }
#pragma unroll
            for (int mi = 0; mi < 4; ++mi)
#pragma unroll
                for (int ni = 0; ni < 4; ++ni)
                    acc[mi][ni] = MFMA16(af[mi], bfr[ni], acc[mi][ni]);
        }
        __syncthreads();
    }

    const int row0 = bmC * 128 + wr + quad * 4;
    const int col0 = bn * 128 + wc + l15;
#pragma unroll
    for (int mi = 0; mi < 4; ++mi)
#pragma unroll
        for (int ni = 0; ni < 4; ++ni)
#pragma unroll
            for (int rx = 0; rx < 4; ++rx)
                storeC(&C[(long)(row0 + mi * 16 + rx) * ldc + col0 + ni * 16],
                       acc[mi][ni][rx]);
}

// ---------------------------------------------------------------------------
// 8-phase 256x256 KV projection GEMM (proven in v10, byte-identical).
// ---------------------------------------------------------------------------
__device__ __forceinline__ void stage_half(
    const __half* __restrict__ M, long row0, int T, char* lds, int slot, int tid)
{
    char* dst = lds + slot * 16384 + tid * 16;
    const int r = tid >> 3;            // 0..63
    const int g = tid & 7;
    const int co = T * 64 + ((g ^ (r & 7)) << 3);
    GLOAD_LDS16(M + (row0 + r) * 2048 + co, dst);
    GLOAD_LDS16(M + (row0 + r + 64) * 2048 + co, dst + 8192);  // (r+64)&7 == r&7
}

__global__ __launch_bounds__(512, 1) void gemm_kv8(
    const __half* __restrict__ A,   // xkv 4096x2048
    const __half* __restrict__ B,   // wkv 4096x2048
    __half* __restrict__ Ckv,       // kvf 4096x4096 (K half: cols 0..2047)
    __half* __restrict__ vT,        // 2048x4096
    const float* __restrict__ kn_w)
{
    __shared__ __align__(16) char LDS[131072];
    const int tid  = threadIdx.x;
    const int lane = tid & 63;
    const int wave = tid >> 6;
    const int wm = wave >> 2;           // 0..1
    const int wn = wave & 3;            // 0..3
    const int l15 = lane & 15, quad = lane >> 4;
    const int bm = blockIdx.x & 15;
    const int bn = blockIdx.x >> 4;
    const long arow = (long)bm * 256;
    const long brow = (long)bn * 256;

    f32x4 acc[8][4] = {};

    stage_half(A, arow,       0, LDS, 0, tid);
    stage_half(A, arow + 128, 0, LDS, 1, tid);
    stage_half(B, brow,       0, LDS, 4, tid);
    stage_half(B, brow + 128, 0, LDS, 5, tid);

    for (int tt = 0; tt < 32; ++tt) {
        const int buf = tt & 1, sbuf = buf ^ 1;
        const int Tn = (tt < 31) ? tt + 1 : 31;
        const __half* As = (const __half*)(LDS + (buf * 2 + wm) * 16384);
        const __half* Bs = (const __half*)(LDS + (4 + buf * 2 + (wn >> 1)) * 16384);
        f16x8 bq[4][2];
#pragma unroll
        for (int q = 0; q < 4; ++q) {
            if (q == 0)      stage_half(A, arow,       Tn, LDS, 0 + sbuf * 2, tid);
            else if (q == 1) stage_half(A, arow + 128, Tn, LDS, 1 + sbuf * 2, tid);
            else if (q == 2) stage_half(B, brow,       Tn, LDS, 4 + sbuf * 2, tid);
            else             stage_half(B, brow + 128, Tn, LDS, 5 + sbuf * 2, tid);
            if (q == 0)
                asm volatile("s_waitcnt vmcnt(2)" ::: "memory");
            __builtin_amdgcn_s_barrier();
            __builtin_amdgcn_sched_barrier(0);
            if (q == 0) {
#pragma unroll
                for (int ni = 0; ni < 4; ++ni) {
                    const int rb = ((wn & 1) << 6) + ni * 16 + l15;
#pragma unroll
                    for (int ks = 0; ks < 2; ++ks)
                        bq[ni][ks] = *(const f16x8*)
                            &Bs[rb * 64 + (((ks * 4 + quad) ^ (rb & 7)) << 3)];
                }
            }
            f16x8 av[2][2];
#pragma unroll
            for (int m2 = 0; m2 < 2; ++m2) {
                const int ra = (q * 2 + m2) * 16 + l15;
#pragma unroll
                for (int ks = 0; ks < 2; ++ks)
                    av[m2][ks] = *(const f16x8*)
                        &As[ra * 64 + (((ks * 4 + quad) ^ (ra & 7)) << 3)];
            }
            __builtin_amdgcn_s_setprio(1);
#pragma unroll
            for (int m2 = 0; m2 < 2; ++m2)
#pragma unroll
                for (int ni = 0; ni < 4; ++ni) {
                    acc[q * 2 + m2][ni] = MFMA16(av[m2][0], bq[ni][0], acc[q * 2 + m2][ni]);
                    acc[q * 2 + m2][ni] = MFMA16(av[m2][1], bq[ni][1], acc[q * 2 + m2][ni]);
                }
            __builtin_amdgcn_s_setprio(0);
            __builtin_amdgcn_s_barrier();
            __builtin_amdgcn_sched_barrier(0);
        }
    }

    __syncthreads();

    if (bn < 8) {
        __half* sT = (__half*)LDS;
#pragma unroll
        for (int mi = 0; mi < 8; ++mi)
#pragma unroll
            for (int ni = 0; ni < 4; ++ni)
#pragma unroll
                for (int rx = 0; rx < 4; ++rx)
                    sT[(wm * 128 + mi * 16 + quad * 4 + rx) * 256 +
                       wn * 64 + ni * 16 + l15] = (_Float16)acc[mi][ni][rx];
        __syncthreads();
        const int row = tid >> 1;
        const int hs  = tid & 1;
        const __half* rp = sT + row * 256 + hs * 128;
        f16x8 xv[16];
#pragma unroll
        for (int j = 0; j < 16; ++j) xv[j] = *(const f16x8*)&rp[j * 8];
        float ss = 0.f;
#pragma unroll
        for (int j = 0; j < 16; ++j)
#pragma unroll
            for (int e = 0; e < 8; ++e) {
                const float v = (float)xv[j][e];
                ss += v * v;
            }
        const float rn = rsqrtf(ss * (1.0f / 128.0f) + 1e-6f);
        const long R = arow + row;
        const float depth = (R < 2048) ? 0.f : 1.f;
        __half* op = Ckv + R * 4096 + bn * 256 + hs * 128;
#pragma unroll
        for (int j = 0; j < 8; ++j) {
            union { f16x8 v; _Float16 e[8]; } o1, o2;
#pragma unroll
            for (int e = 0; e < 8; ++e) {
                const int d = j * 8 + e;
                const float x1 = (float)xv[j][e]     * rn * kn_w[d];
                const float x2 = (float)xv[j + 8][e] * rn * kn_w[d + 64];
                const float ang = depth * exp2f(-(float)d * 0.20762050593045702f);
                float sn, cs;
                __sincosf(ang, &sn, &cs);
                o1.e[e] = (_Float16)(x1 * cs - x2 * sn);
                o2.e[e] = (_Float16)(x1 * sn + x2 * cs);
            }
            *(f16x8*)&op[j * 8]      = o1.v;
            *(f16x8*)&op[64 + j * 8] = o2.v;
        }
    } else {
#pragma unroll
        for (int mi = 0; mi < 8; ++mi)
#pragma unroll
            for (int ni = 0; ni < 4; ++ni)
#pragma unroll
                for (int rx = 0; rx < 4; ++rx) {
                    const int d = (bn - 8) * 256 + wn * 64 + ni * 16 + l15;
                    const long key = arow + wm * 128 + mi * 16 + quad * 4 + rx;
                    vT[(long)d * LKEY + key] = __float2half(acc[mi][ni][rx]);
                }
    }
}

// ---------------------------------------------------------------------------
// Q projection, split-K x2 (fp32 partials): 512 blocks = 2/CU.
// ---------------------------------------------------------------------------
__global__ __launch_bounds__(256, 2) void gemm_skq(
    const __half* __restrict__ A, const __half* __restrict__ Bq,
    float* __restrict__ qp0, float* __restrict__ qp1)
{
    __shared__ __align__(16) __half smem[16384];
    const int z = blockIdx.z;
    float* C = z ? qp1 : qp0;
    gemm_body<0, float>(smem, A + z * 1024, Bq + z * 1024, C,
                        2048, 2048, 2048, 1024,
                        blockIdx.x, blockIdx.x, blockIdx.y);
}

// ---------------------------------------------------------------------------
// Q norm+rope pass: sum the 2 partials, rmsnorm per (row,head), rope depth=2,
// log2(e)/sqrt(D) pre-scale, fp16 out.
// ---------------------------------------------------------------------------
__global__ __launch_bounds__(256) void normrope_q(
    const float* __restrict__ qp0, const float* __restrict__ qp1,
    __half* __restrict__ qf, const float* __restrict__ qn_w)
{
    const int tid  = threadIdx.x;
    const int row  = blockIdx.x * 2 + (tid >> 7);
    const int head = (tid >> 3) & 15;
    const int sub  = tid & 7;
    const long base = (long)row * 2048 + head * 128 + sub * 8;

    const float4 p0a = *(const float4*)&qp0[base];
    const float4 p0b = *(const float4*)&qp0[base + 4];
    const float4 p1a = *(const float4*)&qp1[base];
    const float4 p1b = *(const float4*)&qp1[base + 4];
    const float4 q0a = *(const float4*)&qp0[base + 64];
    const float4 q0b = *(const float4*)&qp0[base + 68];
    const float4 q1a = *(const float4*)&qp1[base + 64];
    const float4 q1b = *(const float4*)&qp1[base + 68];
    float x1[8] = {p0a.x + p1a.x, p0a.y + p1a.y, p0a.z + p1a.z, p0a.w + p1a.w,
                   p0b.x + p1b.x, p0b.y + p1b.y, p0b.z + p1b.z, p0b.w + p1b.w};
    float x2[8] = {q0a.x + q1a.x, q0a.y + q1a.y, q0a.z + q1a.z, q0a.w + q1a.w,
                   q0b.x + q1b.x, q0b.y + q1b.y, q0b.z + q1b.z, q0b.w + q1b.w};

    float ss = 0.f;
#pragma unroll
    for (int j = 0; j < 8; ++j) ss += x1[j] * x1[j] + x2[j] * x2[j];
    ss += __shfl_xor(ss, 1);
    ss += __shfl_xor(ss, 2);
    ss += __shfl_xor(ss, 4);
    const float rn = rsqrtf(ss * (1.0f / 128.0f) + 1e-6f);

    union { f16x8 v; _Float16 e[8]; } o1, o2;
#pragma unroll
    for (int j = 0; j < 8; ++j) {
        const int d = sub * 8 + j;
        const float a1 = x1[j] * rn * qn_w[d];
        const float a2 = x2[j] * rn * qn_w[d + 64];
        const float ang = 2.0f * exp2f(-(float)d * 0.20762050593045702f);
        float sn, cs;
        __sincosf(ang, &sn, &cs);
        o1.e[j] = (_Float16)((a1 * cs - a2 * sn) * 0.12751743f);
        o2.e[j] = (_Float16)((a1 * sn + a2 * cs) * 0.12751743f);
    }
    __half* op = qf + base;
    *(f16x8*)&op[0]  = o1.v;
    *(f16x8*)&op[64] = o2.v;
}

// ---------------------------------------------------------------------------
// Split-K x2 final GEMM: grid (16,16,2) = 512 blocks, (256,2) proven config.
// ---------------------------------------------------------------------------
__global__ __launch_bounds__(256, 2) void gemm_sk(
    const __half* __restrict__ A, const __half* __restrict__ B,
    float* __restrict__ C, int lda, int ldb, int ldc, int Khalf)
{
    __shared__ __align__(16) __half smem[16384];
    const int z = blockIdx.z;
    gemm_body<0, float>(smem, A + z * Khalf, B + z * Khalf,
                        C + (long)z * LQ * CDIM,
                        lda, ldb, ldc, Khalf, blockIdx.x, blockIdx.x, blockIdx.y);
}

// ---------------------------------------------------------------------------
// Fused attention tile kernel (max-free softmax, log2-domain scores).
// v12: ONE change vs v9/v11 — swapped QK^T operands: s = MFMA(kf, aq) so the
// C-layout transposes (reg-quad indexes first-operand=K rows). Each thread
// then holds P[qrow=l15][key=nt*16+quad*4+r2] = 4 CONSECUTIVE keys -> packed
// f16x4 ds_write_b64 (4 stores/step/mt-nt vs 32 scalar b16). ap reads and PV
// unchanged. l_acc becomes a scalar; reduce across quads (xor 16,32).
// ---------------------------------------------------------------------------
__global__ __launch_bounds__(256, 2) void attn_tile(
    const __half* __restrict__ Qf,
    const __half* __restrict__ Kf,
    const __half* __restrict__ Vt,
    float* __restrict__ Opart,
    float* __restrict__ lsum)
{
    __shared__ __align__(16) __half lK[64 * 128];
    __shared__ __align__(16) __half lV[128 * 64];
    __shared__ __align__(16) __half pL[4 * 2 * 16 * 76];

    const int tid  = threadIdx.x;
    const int lane = tid & 63;
    const int wave = tid >> 6;
    const int l15  = lane & 15;
    const int quad = lane >> 4;
    const int lin = blockIdx.y * 16 + blockIdx.x;
    const int hkc = (lin & 7) * 4 + ((lin >> 3) & 3);
    const int qt  = lin >> 5;
    const int h   = hkc >> 1;
    const int kc  = hkc & 1;
    const int q0  = qt * 128 + wave * 32;

    f16x8 aq[2][4];
#pragma unroll
    for (int mt = 0; mt < 2; ++mt)
#pragma unroll
        for (int ks = 0; ks < 4; ++ks)
            aq[mt][ks] = *(const f16x8*)&Qf[(long)(q0 + mt * 16 + l15) * CDIM +
                                            h * HDIM + ks * 32 + quad * 8];

    const int rK = tid >> 4;
    const int gK = tid & 15;
    const __half* srcK = Kf + (long)(kc * 2048 + rK) * 4096 + h * HDIM +
                         ((gK ^ (rK & 15)) << 3);
    const int rV = tid >> 3;
    const int gV = tid & 7;
    const __half* srcV = Vt + (long)(h * HDIM + rV) * (long)LKEY + kc * 2048 +
                         ((gV ^ (rV & 7)) << 3);
    __half* dstK = lK + tid * 8;
    __half* dstV = lV + tid * 8;

    f32x4 accO[2][8] = {};
    float l_acc[2] = {0.f, 0.f};

    for (int st = 0; st < 32; ++st) {
#pragma unroll
        for (int i = 0; i < 4; ++i) {
            GLOAD_LDS16(srcK + (long)(st * 64 + i * 16) * 4096, dstK + i * 2048);
            GLOAD_LDS16(srcV + (long)i * 32 * LKEY + st * 64, dstV + i * 2048);
        }
        __syncthreads();
        // ---- QK^T, swapped operands (acc init -10 folds the exp2 bias) ----
        f32x4 s[2][4];
#pragma unroll
        for (int mt = 0; mt < 2; ++mt)
#pragma unroll
            for (int nt = 0; nt < 4; ++nt)
                s[mt][nt] = (f32x4){-10.f, -10.f, -10.f, -10.f};
#pragma unroll
        for (int nt = 0; nt < 4; ++nt) {
            const int n = nt * 16 + l15;
#pragma unroll
            for (int ks = 0; ks < 4; ++ks) {
                const f16x8 kf = *(const f16x8*)
                    &lK[n * 128 + (((ks * 4 + quad) ^ (n & 15)) << 3)];
                s[0][nt] = MFMA16(kf, aq[0][ks], s[0][nt]);
                s[1][nt] = MFMA16(kf, aq[1][ks], s[1][nt]);
            }
        }
        // ---- P = exp2(s): thread holds row=l15, keys nt*16+quad*4+r2 ----
        // packed f16x4 b64 stores (4/mt vs 32 scalar b16); exact 4-way banks.
#pragma unroll
        for (int mt = 0; mt < 2; ++mt) {
            __half* slab = pL + ((wave * 2 + mt) * 16 + l15) * 76;
#pragma unroll
            for (int nt = 0; nt < 4; ++nt) {
                union { f16x4 v; _Float16 e[4]; } pk;
#pragma unroll
                for (int r2 = 0; r2 < 4; ++r2) {
                    const float p = __builtin_amdgcn_exp2f(s[mt][nt][r2]);
                    l_acc[mt] += p;
                    pk.e[r2] = (_Float16)p;
                }
                *(f16x4*)&slab[nt * 16 + quad * 4] = pk.v;
            }
        }
        // ---- PV (ap reads unchanged: row l15, cols quad*8..+7 / +32) ----
        f16x8 ap[2][2];
#pragma unroll
        for (int mt = 0; mt < 2; ++mt) {
            ap[mt][0] = *(const f16x8*)&pL[((wave * 2 + mt) * 16 + l15) * 76 + quad * 8];
            ap[mt][1] = *(const f16x8*)&pL[((wave * 2 + mt) * 16 + l15) * 76 + 32 + quad * 8];
        }
#pragma unroll
        for (int nt2 = 0; nt2 < 8; ++nt2) {
            const int n2 = nt2 * 16 + l15;
            const f16x8 v0 = *(const f16x8*)&lV[n2 * 64 + ((quad ^ (n2 & 7)) << 3)];
            const f16x8 v1 = *(const f16x8*)&lV[n2 * 64 + (((4 + quad) ^ (n2 & 7)) << 3)];
            accO[0][nt2] = MFMA16(ap[0][0], v0, accO[0][nt2]);
            accO[0][nt2] = MFMA16(ap[0][1], v1, accO[0][nt2]);
            accO[1][nt2] = MFMA16(ap[1][0], v0, accO[1][nt2]);
            accO[1][nt2] = MFMA16(ap[1][1], v1, accO[1][nt2]);
        }
        __syncthreads();
    }

    // ---- l: per-thread scalar covers 16 keys of row l15; sum across quads
#pragma unroll
    for (int mt = 0; mt < 2; ++mt) {
        float v = l_acc[mt];
        v += __shfl_xor(v, 16);
        v += __shfl_xor(v, 32);
        if (lane < 16)
            atomicAdd(&lsum[h * LQ + q0 + mt * 16 + lane], v);
    }
    // ---- O partial (fp32) ----
    float* Cp = Opart + (long)kc * LQ * CDIM + h * HDIM;
#pragma unroll
    for (int mt = 0; mt < 2; ++mt)
#pragma unroll
        for (int nt2 = 0; nt2 < 8; ++nt2)
#pragma unroll
            for (int rx = 0; rx < 4; ++rx)
                Cp[(long)(q0 + mt * 16 + quad * 4 + rx) * CDIM + nt2 * 16 + l15] =
                    accO[mt][nt2][rx];
}

// ---------------------------------------------------------------------------
// merge: a2[q][c] = (Op0+Op1)[q][c] / lsum[c>>7][q]   (fp16 out)
// ---------------------------------------------------------------------------
__global__ __launch_bounds__(256) void merge_o(
    const float* __restrict__ Op, const float* __restrict__ lsum,
    __half* __restrict__ a2)
{
    const int row = blockIdx.x;
    const int c0  = threadIdx.x * 8;
    const float inv = 1.0f / lsum[(c0 >> 7) * LQ + row];
    const float* p0 = Op + (long)row * CDIM + c0;
    const float* p1 = p0 + (long)LQ * CDIM;
    union { f16x8 v; _Float16 e[8]; } o;
#pragma unroll
    for (int j = 0; j < 8; ++j)
        o.e[j] = (_Float16)((p0[j] + p1[j]) * inv);
    *(f16x8*)&a2[(long)row * 4096 + c0] = o.v;
}

// ---------------------------------------------------------------------------
// ONE prep launch: 6 casts + Wo pack + sw2^T + sin features + lsum zero.
// ---------------------------------------------------------------------------
__global__ __launch_bounds__(256) void prep_all(
    const float* __restrict__ h2, const float* __restrict__ h0,
    const float* __restrict__ h1, const float* __restrict__ Wq,
    const float* __restrict__ Wk, const float* __restrict__ Wv,
    const float* __restrict__ Wo, const float* __restrict__ sw1,
    const float* __restrict__ sb1, const float* __restrict__ sw2,
    __half* __restrict__ xq, __half* __restrict__ xkv,
    __half* __restrict__ wqh, __half* __restrict__ wkv,
    __half* __restrict__ a2, __half* __restrict__ b2,
    float* __restrict__ lsum)
{
    __shared__ float t[64][65];
    const int blk = blockIdx.x;
    const int tid = threadIdx.x;
    if (blk < 24576) {
        const long i = ((long)blk * 256 + tid) << 2;
        const int chunk = (int)(i >> 22);
        const long off = i & 4194303;
        const float* s; __half* d;
        switch (chunk) {
            case 0:  s = h2; d = xq;            break;
            case 1:  s = h0; d = xkv;           break;
            case 2:  s = h1; d = xkv + 4194304; break;
            case 3:  s = Wq; d = wqh;           break;
            case 4:  s = Wk; d = wkv;           break;
            default: s = Wv; d = wkv + 4194304; break;
        }
        const float4 v = *(const float4*)&s[off];
        f16x4 o;
        o[0] = (_Float16)v.x; o[1] = (_Float16)v.y;
        o[2] = (_Float16)v.z; o[3] = (_Float16)v.w;
        *(f16x4*)&d[off] = o;
    } else if (blk < 28672) {
        const int i = ((blk - 24576) * 256 + tid) << 2;
        const int o = i >> 11, c = i & 2047;
        const float4 v = *(const float4*)&Wo[i];
        f16x4 w4;
        w4[0] = (_Float16)v.x; w4[1] = (_Float16)v.y;
        w4[2] = (_Float16)v.z; w4[3] = (_Float16)v.w;
        *(f16x4*)&b2[((long)o << 12) + c] = w4;
    } else if (blk < 29696) {
        const int lb = blk - 28672;
        const long r0 = (long)(lb & 31) * 64;
        const long c0 = (long)(lb >> 5) * 64;
        const int tj = tid & 63;
        const int ti = tid >> 6;
#pragma unroll
        for (int it = 0; it < 16; ++it) {
            const int i = it * 4 + ti;
            t[i][tj] = sw2[(r0 + i) * 2048 + c0 + tj];
        }
        __syncthreads();
#pragma unroll
        for (int it = 0; it < 16; ++it) {
            const int i = it * 4 + ti;
            b2[(c0 + i) * 4096 + 2048 + r0 + tj] = __float2half(t[tj][i]);
        }
    } else if (blk < 33792) {
        const int i = ((blk - 29696) * 256 + tid) << 2;
        const int l = i >> 11, c = i & 2047;
        const float coord = -1.0f + (2.0f / 2047.0f) * (float)l;
        const float4 w = *(const float4*)&sw1[c];
        const float4 b = *(const float4*)&sb1[c];
        f16x4 o;
        o[0] = (_Float16)__sinf(30.0f * (coord * w.x + b.x));
        o[1] = (_Float16)__sinf(30.0f * (coord * w.y + b.y));
        o[2] = (_Float16)__sinf(30.0f * (coord * w.z + b.z));
        o[3] = (_Float16)__sinf(30.0f * (coord * w.w + b.w));
        *(f16x4*)&a2[((long)l << 12) + 2048 + c] = o;
    } else {
        const int i = ((blk - 33792) * 256 + tid) << 2;
        *(float4*)&lsum[i] = (float4){0.f, 0.f, 0.f, 0.f};
    }
}

__global__ __launch_bounds__(256) void final_norm(
    const float* __restrict__ out2, const float* __restrict__ x,
    const float* __restrict__ sb2, const float* __restrict__ on_w,
    float* __restrict__ y)
{
    const int row = blockIdx.x;
    const float* o0 = out2 + (long)row * CDIM;
    const float* o1 = o0 + (long)LQ * CDIM;
    float4 v[2];
    float ss = 0.f;
#pragma unroll
    for (int i = 0; i < 2; ++i) {
        const int c = threadIdx.x * 4 + i * 1024;
        const float4 a = *(const float4*)&o0[c];
        const float4 b = *(const float4*)&o1[c];
        const float4 s = *(const float4*)&sb2[c];
        float4 tv;
        tv.x = a.x + b.x + s.x; tv.y = a.y + b.y + s.y;
        tv.z = a.z + b.z + s.z; tv.w = a.w + b.w + s.w;
        v[i] = tv;
        ss += tv.x * tv.x + tv.y * tv.y + tv.z * tv.z + tv.w * tv.w;
    }
#pragma unroll
    for (int off = 1; off < 64; off <<= 1) ss += __shfl_xor(ss, off);
    __shared__ float red[4];
    const int lane = threadIdx.x & 63, wv = threadIdx.x >> 6;
    if (lane == 0) red[wv] = ss;
    __syncthreads();
    const float tot = red[0] + red[1] + red[2] + red[3];
    const float rn = rsqrtf(tot * (1.0f / 2048.0f) + 1e-6f);
#pragma unroll
    for (int i = 0; i < 2; ++i) {
        const int c = threadIdx.x * 4 + i * 1024;
        const float4 xr = *(const float4*)&x[(long)row * CDIM + c];
        const float4 wv4 = *(const float4*)&on_w[c];
        float4 o;
        o.x = xr.x + v[i].x * rn * wv4.x;
        o.y = xr.y + v[i].y * rn * wv4.y;
        o.z = xr.z + v[i].z * rn * wv4.z;
        o.w = xr.w + v[i].w * rn * wv4.w;
        *(float4*)&y[(long)row * CDIM + c] = o;
    }
}

// ---------------------------------------------------------------------------
extern "C" void kernel_launch(void* const* d_in, const int* in_sizes, int n_in,
                              void* d_out, int out_size, void* d_ws, size_t ws_size,
                              hipStream_t stream) {
    const float* x    = (const float*)d_in[0];
    const float* h0   = (const float*)d_in[1];
    const float* h1   = (const float*)d_in[2];
    const float* h2   = (const float*)d_in[3];
    const float* Wq   = (const float*)d_in[4];
    const float* Wk   = (const float*)d_in[5];
    const float* Wv   = (const float*)d_in[6];
    const float* Wo   = (const float*)d_in[7];
    const float* qn_w = (const float*)d_in[8];
    const float* kn_w = (const float*)d_in[9];
    const float* on_w = (const float*)d_in[10];
    const float* sw1  = (const float*)d_in[11];
    const float* sb1  = (const float*)d_in[12];
    const float* sw2  = (const float*)d_in[13];
    const float* sb2  = (const float*)d_in[14];
    float* y = (float*)d_out;

    const size_t MB = 1ull << 20;
    char* w = (char*)d_ws;
    __half* xq  = (__half*)(w);             //  8 MB  h2 fp16
    __half* xkv = (__half*)(w + 8 * MB);    // 16 MB  [h0;h1] fp16 (dead after kv8)
    __half* wqh = (__half*)(w + 24 * MB);   //  8 MB  Wq fp16
    __half* wkv = (__half*)(w + 32 * MB);   // 16 MB  [Wk;Wv] fp16 (dead after kv8)
    __half* qf  = (__half*)(w + 48 * MB);   //  8 MB  Q proj, normed+roped
    __half* kvf = (__half*)(w + 56 * MB);   // 32 MB  K normed (cols 0..2047)
    __half* vT  = (__half*)(w + 88 * MB);   // 16 MB  V transposed (2048x4096)
    __half* a2  = (__half*)(w + 104 * MB);  // 16 MB  [attn_out | sin_feat]
    __half* b2  = (__half*)(w + 120 * MB);  // 16 MB  [Wo | sw2^T]
    float* lsum  = (float*)(w + 136 * MB);  // 128 KB (zeroed in prep)
    float* qp0   = (float*)(w + 8 * MB);    // 16 MB  Q split-K partial 0 (xkv, dead)
    float* qp1   = (float*)(w + 32 * MB);   // 16 MB  Q split-K partial 1 (wkv, dead)
    float* Opart = (float*)(w);             // 32 MB  overlays xq/xkv (dead after skq)
    float* out2  = (float*)(w);             // 32 MB  [2] split-K partials
    (void)in_sizes; (void)n_in; (void)out_size; (void)ws_size;

    prep_all<<<33824, 256, 0, stream>>>(h2, h0, h1, Wq, Wk, Wv, Wo, sw1, sb1,
                                        sw2, xq, xkv, wqh, wkv, a2, b2, lsum);

    // KV projection: 8-phase 256² kernel (norm+rope K, transposed V)
    gemm_kv8<<<256, 512, 0, stream>>>(xkv, wkv, kvf, vT, kn_w);
    // Q projection: split-K x2 into fp32 partials (2 blocks/CU regime) + norm pass
    gemm_skq<<<dim3(16, 16, 2), 256, 0, stream>>>(xq, wqh, qp0, qp1);
    normrope_q<<<1024, 256, 0, stream>>>(qp0, qp1, qf, qn_w);

    attn_tile<<<dim3(16, 32), 256, 0, stream>>>(qf, kvf, vT, Opart, lsum);
    merge_o<<<2048, 256, 0, stream>>>(Opart, lsum, a2);

    gemm_sk<<<dim3(16, 16, 2), 256, 0, stream>>>(a2, b2, out2, 4096, 4096, 2048, 2048);
    final_norm<<<2048, 256, 0, stream>>>(out2, x, sb2, on_w, y);
}